// Round 1
// baseline (2664.412 us; speedup 1.0000x reference)
//
#include <hip/hip_runtime.h>
#include <cstddef>

// ---------------- workspace layout (float offsets) ----------------
// joint = [visual(512) | semantic(512) | gcn512(512)] must be contiguous.
static constexpr size_t OFF_VIS  = 0;          // 512
static constexpr size_t OFF_SEM  = 512;        // 512
static constexpr size_t OFF_GCN  = 1024;       // 512
static constexpr size_t OFF_S512 = 1536;       // 512
static constexpr size_t OFF_VROW = 2048;       // 1024
static constexpr size_t OFF_X    = 3072;       // 512
static constexpr size_t OFF_Y3   = 4096;       // 4096
static constexpr size_t OFF_H3   = 8192;       // 4096
static constexpr size_t OFF_BUF0 = 16384;                  // 4M floats: em (2M used), later H2
static constexpr size_t OFF_BUF1 = OFF_BUF0 + 4194304;     // 4M: Y1, later Y2
static constexpr size_t OFF_BUF2 = OFF_BUF1 + 4194304;     // 4M: H1

// ---------------- block reduction ----------------
__device__ inline float blockReduceSum256(float v) {
    #pragma unroll
    for (int o = 32; o > 0; o >>= 1) v += __shfl_down(v, o, 64);
    __shared__ float red[4];
    int w = threadIdx.x >> 6;
    if ((threadIdx.x & 63) == 0) red[w] = v;
    __syncthreads();
    if (threadIdx.x == 0) v = red[0] + red[1] + red[2] + red[3];
    return v;  // valid on thread 0 only
}

// ---------------- K1: the three input-side GEMVs ----------------
// blocks 0..511: visual (K=8192), 512..1023: semantic (K=300), 1024..1535: scores_512 (K=1000)
__global__ void vec3_kernel(const float* __restrict__ frames,
                            const float* __restrict__ scores,
                            const float* __restrict__ word_embed,
                            const float* __restrict__ visual_W, const float* __restrict__ visual_b,
                            const float* __restrict__ semantic_W, const float* __restrict__ semantic_b,
                            const float* __restrict__ score_W, const float* __restrict__ score_b,
                            float* __restrict__ ws) {
    int b = blockIdx.x;
    const float* x; const float* W; const float* bias; float* out; int K; int row;
    if (b < 512)       { row = b;        x = frames;     W = visual_W;   bias = visual_b;   out = ws + OFF_VIS;  K = 8192; }
    else if (b < 1024) { row = b - 512;  x = word_embed; W = semantic_W; bias = semantic_b; out = ws + OFF_SEM;  K = 300;  }
    else               { row = b - 1024; x = scores;     W = score_W;    bias = score_b;    out = ws + OFF_S512; K = 1000; }
    const float* wr = W + (size_t)row * K;
    float s = 0.f;
    for (int k = threadIdx.x; k < K; k += 256) s += wr[k] * x[k];
    s = blockReduceSum256(s);
    if (threadIdx.x == 0) out[row] = fmaxf(s + bias[row], 0.f);
}

// ---------------- K2: vrow1[j] = sum_k s512[k] * gc1_W[k, j]   (k<512, j<1024) ----------------
__global__ void vrow_kernel(const float* __restrict__ gc1_W, float* __restrict__ ws) {
    int j = blockIdx.x * 256 + threadIdx.x;
    const float* s512 = ws + OFF_S512;
    float s = 0.f;
    for (int k = 0; k < 512; k++) s += s512[k] * gc1_W[(size_t)k * 1024 + j];
    ws[OFF_VROW + j] = s;
}

// ---------------- tiled f32 GEMM: C[M,N] = A[M,K] @ B + (vrow) + (bias), opt relu ----------
// TRANSB=1: B stored [N,K] (K-contiguous);  TRANSB=0: B stored [K,N] (N-contiguous)
template<int TRANSB>
__global__ __launch_bounds__(256) void gemm_f32_128(
    const float* __restrict__ A, const float* __restrict__ B, float* __restrict__ C,
    int M, int N, int K, int lda, int ldb,
    const float* __restrict__ bias, const float* __restrict__ vrow, int do_relu)
{
    constexpr int BM = 128, BN = 128, BK = 16;
    __shared__ float As[BK][BM + 4];
    __shared__ float Bs[BK][BN + 4];
    const int t = threadIdx.x;
    const int w = t >> 6, l = t & 63;
    const int cx = (w & 1) * 8 + (l & 7);    // 0..15 col-group
    const int cy = (w >> 1) * 8 + (l >> 3);  // 0..15 row-group
    const int row0 = blockIdx.y * BM;
    const int col0 = blockIdx.x * BN;

    float acc[8][8];
    #pragma unroll
    for (int i = 0; i < 8; i++)
        #pragma unroll
        for (int j = 0; j < 8; j++) acc[i][j] = 0.f;

    const int ka = t & 15;   // staging k index (A / transposed-B)
    const int ma = t >> 4;   // staging row base

    for (int k0 = 0; k0 < K; k0 += BK) {
        // stage A tile (BM x BK), k-major in LDS
        #pragma unroll
        for (int i = 0; i < 8; i++) {
            int m = ma + i * 16;
            int gk = k0 + ka;
            float v = 0.f;
            if (gk < K) v = A[(size_t)(row0 + m) * lda + gk];
            As[ka][m] = v;
        }
        if (TRANSB) {
            #pragma unroll
            for (int i = 0; i < 8; i++) {
                int n = ma + i * 16;
                int gk = k0 + ka;
                float v = 0.f;
                if (gk < K) v = B[(size_t)(col0 + n) * ldb + gk];
                Bs[ka][n] = v;
            }
        } else {
            const int nb = t & 127;
            const int kb = t >> 7;   // 0..1
            #pragma unroll
            for (int i = 0; i < 8; i++) {
                int kk = kb + i * 2;
                int gk = k0 + kk;
                float v = 0.f;
                if (gk < K) v = B[(size_t)gk * ldb + col0 + nb];
                Bs[kk][nb] = v;
            }
        }
        __syncthreads();
        #pragma unroll
        for (int kk = 0; kk < BK; kk++) {
            float a[8], bb[8];
            *(float4*)&a[0]  = *(const float4*)&As[kk][cy * 8];
            *(float4*)&a[4]  = *(const float4*)&As[kk][cy * 8 + 4];
            *(float4*)&bb[0] = *(const float4*)&Bs[kk][cx * 8];
            *(float4*)&bb[4] = *(const float4*)&Bs[kk][cx * 8 + 4];
            #pragma unroll
            for (int i = 0; i < 8; i++)
                #pragma unroll
                for (int j = 0; j < 8; j++)
                    acc[i][j] = fmaf(a[i], bb[j], acc[i][j]);
        }
        __syncthreads();
    }

    // epilogue
    #pragma unroll
    for (int i = 0; i < 8; i++) {
        int r = row0 + cy * 8 + i;
        float vv[8];
        #pragma unroll
        for (int j = 0; j < 8; j++) {
            int c = col0 + cx * 8 + j;
            float v = acc[i][j];
            if (vrow) v += vrow[c];
            if (bias) v += bias[c];
            if (do_relu) v = fmaxf(v, 0.f);
            vv[j] = v;
        }
        float* cp = C + (size_t)r * N + col0 + cx * 8;
        *(float4*)cp       = *(float4*)&vv[0];
        *(float4*)(cp + 4) = *(float4*)&vv[4];
    }
}

// ---------------- K7: y3[i] = H2[i,:] . gc3_W  (K=1024, no bias) ----------------
__global__ void y3_kernel(const float* __restrict__ H2, const float* __restrict__ gc3_W,
                          float* __restrict__ ws) {
    int i = blockIdx.x;
    const float* r = H2 + (size_t)i * 1024;
    float s = 0.f;
    for (int k = threadIdx.x; k < 1024; k += 256) s += r[k] * gc3_W[k];
    s = blockReduceSum256(s);
    if (threadIdx.x == 0) ws[OFF_Y3 + i] = s;
}

// ---------------- K8: h3[i] = relu(adj[i,:] . y3 + gc3_b[0]) ----------------
__global__ void h3_kernel(const float* __restrict__ adj, const float* __restrict__ gc3_b,
                          float* __restrict__ ws) {
    int i = blockIdx.x;
    const float* r = adj + (size_t)i * 4096;
    const float* y3 = ws + OFF_Y3;
    float s = 0.f;
    for (int k = threadIdx.x; k < 4096; k += 256) s += r[k] * y3[k];
    s = blockReduceSum256(s);
    if (threadIdx.x == 0) ws[OFF_H3 + i] = fmaxf(s + gc3_b[0], 0.f);
}

// ---------------- K9: gcn512[j] = relu(gcn512_W[j,:] . h3 + b[j])  (K=4096) ----------------
__global__ void gcn_kernel(const float* __restrict__ gcn512_W, const float* __restrict__ gcn512_b,
                           float* __restrict__ ws) {
    int j = blockIdx.x;
    const float* r = gcn512_W + (size_t)j * 4096;
    const float* h3 = ws + OFF_H3;
    float s = 0.f;
    for (int k = threadIdx.x; k < 4096; k += 256) s += r[k] * h3[k];
    s = blockReduceSum256(s);
    if (threadIdx.x == 0) ws[OFF_GCN + j] = fmaxf(s + gcn512_b[j], 0.f);
}

// ---------------- K10: x[j] = relu(hidden_W[j,:] . joint + b[j])  (K=1536) ----------------
__global__ void x_kernel(const float* __restrict__ hidden_W, const float* __restrict__ hidden_b,
                         float* __restrict__ ws) {
    int j = blockIdx.x;
    const float* r = hidden_W + (size_t)j * 1536;
    const float* joint = ws;  // [visual|semantic|gcn]
    float s = 0.f;
    for (int k = threadIdx.x; k < 1536; k += 256) s += r[k] * joint[k];
    s = blockReduceSum256(s);
    if (threadIdx.x == 0) ws[OFF_X + j] = fmaxf(s + hidden_b[j], 0.f);
}

// ---------------- K11: critic + actor -> d_out[7] ----------------
__global__ void out_kernel(const float* __restrict__ ws,
                           const float* __restrict__ critic_W, const float* __restrict__ critic_b,
                           const float* __restrict__ actor_W, const float* __restrict__ actor_b,
                           float* __restrict__ out) {
    const float* xv = ws + OFF_X;
    int w = threadIdx.x >> 6, l = threadIdx.x & 63;
    if (w >= 7) return;
    const float* row = (w == 0) ? critic_W : actor_W + (size_t)(w - 1) * 512;
    float s = 0.f;
    for (int q = l; q < 512; q += 64) s += xv[q] * row[q];
    #pragma unroll
    for (int o = 32; o > 0; o >>= 1) s += __shfl_down(s, o, 64);
    if (l == 0) out[w] = s + ((w == 0) ? critic_b[0] : actor_b[w - 1]);
}

// ---------------- host launcher ----------------
extern "C" void kernel_launch(void* const* d_in, const int* in_sizes, int n_in,
                              void* d_out, int out_size, void* d_ws, size_t ws_size,
                              hipStream_t stream) {
    const float* frames     = (const float*)d_in[0];
    const float* scores     = (const float*)d_in[1];
    const float* word_embed = (const float*)d_in[2];
    const float* all_embeds = (const float*)d_in[3];
    const float* adj        = (const float*)d_in[4];
    const float* visual_W   = (const float*)d_in[5];
    const float* visual_b   = (const float*)d_in[6];
    const float* semantic_W = (const float*)d_in[7];
    const float* semantic_b = (const float*)d_in[8];
    const float* score_W    = (const float*)d_in[9];
    const float* score_b    = (const float*)d_in[10];
    const float* gc1_W      = (const float*)d_in[11];
    const float* gc1_b      = (const float*)d_in[12];
    const float* gc2_W      = (const float*)d_in[13];
    const float* gc2_b      = (const float*)d_in[14];
    const float* gc3_W      = (const float*)d_in[15];
    const float* gc3_b      = (const float*)d_in[16];
    const float* gcn512_W   = (const float*)d_in[17];
    const float* gcn512_b   = (const float*)d_in[18];
    const float* hidden_W   = (const float*)d_in[19];
    const float* hidden_b   = (const float*)d_in[20];
    const float* critic_W   = (const float*)d_in[21];
    const float* critic_b   = (const float*)d_in[22];
    const float* actor_W    = (const float*)d_in[23];
    const float* actor_b    = (const float*)d_in[24];

    float* ws  = (float*)d_ws;
    float* out = (float*)d_out;

    float* em = ws + OFF_BUF0;   // [4096,512]
    float* Y1 = ws + OFF_BUF1;   // [4096,1024]
    float* H1 = ws + OFF_BUF2;   // [4096,1024]
    float* Y2 = ws + OFF_BUF1;   // reuse
    float* H2 = ws + OFF_BUF0;   // reuse (em is dead)

    // 1. visual / semantic / scores_512
    vec3_kernel<<<1536, 256, 0, stream>>>(frames, scores, word_embed,
                                          visual_W, visual_b, semantic_W, semantic_b,
                                          score_W, score_b, ws);
    // 2. vrow1 = s512 @ gc1_W[:512,:]
    vrow_kernel<<<4, 256, 0, stream>>>(gc1_W, ws);
    // 3. em = relu(all_embeds @ semantic_W.T + semantic_b)   [4096,512], K=300 (NT)
    gemm_f32_128<1><<<dim3(512 / 128, 4096 / 128), 256, 0, stream>>>(
        all_embeds, semantic_W, em, 4096, 512, 300, 300, 300, semantic_b, nullptr, 1);
    // 4. Y1 = em @ gc1_W[512:,:] + vrow1          [4096,1024], K=512 (NN)
    gemm_f32_128<0><<<dim3(1024 / 128, 4096 / 128), 256, 0, stream>>>(
        em, gc1_W + (size_t)512 * 1024, Y1, 4096, 1024, 512, 512, 1024,
        nullptr, ws + OFF_VROW, 0);
    // 5. H1 = relu(adj @ Y1 + gc1_b)              [4096,1024], K=4096 (NN)
    gemm_f32_128<0><<<dim3(1024 / 128, 4096 / 128), 256, 0, stream>>>(
        adj, Y1, H1, 4096, 1024, 4096, 4096, 1024, gc1_b, nullptr, 1);
    // 6. Y2 = H1 @ gc2_W                          [4096,1024], K=1024 (NN)
    gemm_f32_128<0><<<dim3(1024 / 128, 4096 / 128), 256, 0, stream>>>(
        H1, gc2_W, Y2, 4096, 1024, 1024, 1024, 1024, nullptr, nullptr, 0);
    // 7. H2 = relu(adj @ Y2 + gc2_b)              [4096,1024], K=4096 (NN)
    gemm_f32_128<0><<<dim3(1024 / 128, 4096 / 128), 256, 0, stream>>>(
        adj, Y2, H2, 4096, 1024, 4096, 4096, 1024, gc2_b, nullptr, 1);
    // 8. y3 = H2 @ gc3_W
    y3_kernel<<<4096, 256, 0, stream>>>(H2, gc3_W, ws);
    // 9. h3 = relu(adj @ y3 + gc3_b)
    h3_kernel<<<4096, 256, 0, stream>>>(adj, gc3_b, ws);
    // 10. gcn512 = relu(gcn512_W @ h3 + b)
    gcn_kernel<<<512, 256, 0, stream>>>(gcn512_W, gcn512_b, ws);
    // 11. x = relu(hidden_W @ joint + b)
    x_kernel<<<512, 256, 0, stream>>>(hidden_W, hidden_b, ws);
    // 12. critic + actor
    out_kernel<<<1, 512, 0, stream>>>(ws, critic_W, critic_b, actor_W, actor_b, out);

    (void)in_sizes; (void)n_in; (void)out_size; (void)ws_size;
}

// Round 2
// 394.249 us; speedup vs baseline: 6.7582x; 6.7582x over previous
//
#include <hip/hip_runtime.h>
#include <cstddef>
#include <cstdint>

typedef unsigned short ushort_t;
typedef short  s16x8 __attribute__((ext_vector_type(8)));
typedef float  f32x4 __attribute__((ext_vector_type(4)));
typedef unsigned short u16x4 __attribute__((ext_vector_type(4)));

typedef __attribute__((address_space(1))) const void gas_void;
typedef __attribute__((address_space(3))) void las_void;

// ---------------- bf16 helpers ----------------
__device__ __forceinline__ unsigned short f2bh(float x) {
    union { float f; unsigned int u; } c; c.f = x;
    unsigned int r = c.u + 0x7fffu + ((c.u >> 16) & 1u);
    return (unsigned short)(r >> 16);
}
__device__ __forceinline__ float bh2f(unsigned short h) {
    union { unsigned int u; float f; } c; c.u = ((unsigned int)h) << 16;
    return c.f;
}

__device__ __forceinline__ f32x4 MF(s16x8 a, s16x8 b, f32x4 c) {
    return __builtin_amdgcn_mfma_f32_16x16x32_bf16(a, b, c, 0, 0, 0);
}
__device__ __forceinline__ void gload16(const unsigned short* g, unsigned short* l) {
    __builtin_amdgcn_global_load_lds((gas_void*)g, (las_void*)l, 16, 0, 0);
}

// ---------------- shared small-vector offsets (floats, relative to vec base) -------------
static constexpr size_t OFF_VIS  = 0;
static constexpr size_t OFF_SEM  = 512;
static constexpr size_t OFF_GCN  = 1024;
static constexpr size_t OFF_S512 = 1536;
static constexpr size_t OFF_VROW = 2048;
static constexpr size_t OFF_X    = 3072;
static constexpr size_t OFF_Y3   = 4096;
static constexpr size_t OFF_H3   = 8192;
// fallback big buffers (floats, absolute in ws)
static constexpr size_t OFF_BUF0 = 16384;
static constexpr size_t OFF_BUF1 = OFF_BUF0 + 4194304;
static constexpr size_t OFF_BUF2 = OFF_BUF1 + 4194304;

// ---------------- fast-path ws layout (bytes) ----------------
static constexpr size_t B_ADJH  = 0;                       // 4096*4096*2 = 33554432
static constexpr size_t B_EMB_H = 33554432;                // 4096*320*2
static constexpr size_t B_EMB_L = B_EMB_H + 2621440;
static constexpr size_t B_SW_H  = B_EMB_L + 2621440;       // 512*320*2
static constexpr size_t B_SW_L  = B_SW_H + 327680;
static constexpr size_t B_W1T_H = B_SW_L + 327680;         // 1024*512*2
static constexpr size_t B_W1T_L = B_W1T_H + 1048576;
static constexpr size_t B_W2T_H = B_W1T_L + 1048576;       // 1024*1024*2
static constexpr size_t B_W2T_L = B_W2T_H + 2097152;
static constexpr size_t B_EM_H  = B_W2T_L + 2097152;       // 4096*512*2
static constexpr size_t B_EM_L  = B_EM_H + 4194304;
static constexpr size_t B_H2F   = B_EMB_H;                 // 4096*1024*4 aliases dead pool
static constexpr size_t B_Y1T_H = B_EM_L + 4194304;        // 1024*4096*2
static constexpr size_t B_Y1T_L = B_Y1T_H + 8388608;
static constexpr size_t B_H1_H  = B_Y1T_L + 8388608;
static constexpr size_t B_H1_L  = B_H1_H + 8388608;
static constexpr size_t B_VEC   = B_H1_L + 8388608;        // 12288 floats
static constexpr size_t FAST_WS = B_VEC + 49152;

// ---------------- block reduction ----------------
__device__ inline float blockReduceSum256(float v) {
    #pragma unroll
    for (int o = 32; o > 0; o >>= 1) v += __shfl_down(v, o, 64);
    __shared__ float red[4];
    int w = threadIdx.x >> 6;
    if ((threadIdx.x & 63) == 0) red[w] = v;
    __syncthreads();
    if (threadIdx.x == 0) v = red[0] + red[1] + red[2] + red[3];
    return v;
}

// ---------------- small kernels (shared by both paths) ----------------
__global__ void vec3_kernel(const float* __restrict__ frames,
                            const float* __restrict__ scores,
                            const float* __restrict__ word_embed,
                            const float* __restrict__ visual_W, const float* __restrict__ visual_b,
                            const float* __restrict__ semantic_W, const float* __restrict__ semantic_b,
                            const float* __restrict__ score_W, const float* __restrict__ score_b,
                            float* __restrict__ vec) {
    int b = blockIdx.x;
    const float* x; const float* W; const float* bias; float* out; int K; int row;
    if (b < 512)       { row = b;        x = frames;     W = visual_W;   bias = visual_b;   out = vec + OFF_VIS;  K = 8192; }
    else if (b < 1024) { row = b - 512;  x = word_embed; W = semantic_W; bias = semantic_b; out = vec + OFF_SEM;  K = 300;  }
    else               { row = b - 1024; x = scores;     W = score_W;    bias = score_b;    out = vec + OFF_S512; K = 1000; }
    const float* wr = W + (size_t)row * K;
    float s = 0.f;
    for (int k = threadIdx.x; k < K; k += 256) s += wr[k] * x[k];
    s = blockReduceSum256(s);
    if (threadIdx.x == 0) out[row] = fmaxf(s + bias[row], 0.f);
}

__global__ void vrow_kernel(const float* __restrict__ gc1_W, float* __restrict__ vec) {
    int j = blockIdx.x * 256 + threadIdx.x;
    const float* s512 = vec + OFF_S512;
    float s = 0.f;
    for (int k = 0; k < 512; k++) s += s512[k] * gc1_W[(size_t)k * 1024 + j];
    vec[OFF_VROW + j] = s;
}

__global__ void y3_kernel(const float* __restrict__ H2, const float* __restrict__ gc3_W,
                          float* __restrict__ vec) {
    int i = blockIdx.x;
    const float* r = H2 + (size_t)i * 1024;
    float s = 0.f;
    for (int k = threadIdx.x; k < 1024; k += 256) s += r[k] * gc3_W[k];
    s = blockReduceSum256(s);
    if (threadIdx.x == 0) vec[OFF_Y3 + i] = s;
}

__global__ void h3_kernel(const float* __restrict__ adj, const float* __restrict__ gc3_b,
                          float* __restrict__ vec) {
    int i = blockIdx.x;
    const float* r = adj + (size_t)i * 4096;
    const float* y3 = vec + OFF_Y3;
    float s = 0.f;
    for (int k = threadIdx.x; k < 4096; k += 256) s += r[k] * y3[k];
    s = blockReduceSum256(s);
    if (threadIdx.x == 0) vec[OFF_H3 + i] = fmaxf(s + gc3_b[0], 0.f);
}

__global__ void gcn_kernel(const float* __restrict__ gcn512_W, const float* __restrict__ gcn512_b,
                           float* __restrict__ vec) {
    int j = blockIdx.x;
    const float* r = gcn512_W + (size_t)j * 4096;
    const float* h3 = vec + OFF_H3;
    float s = 0.f;
    for (int k = threadIdx.x; k < 4096; k += 256) s += r[k] * h3[k];
    s = blockReduceSum256(s);
    if (threadIdx.x == 0) vec[OFF_GCN + j] = fmaxf(s + gcn512_b[j], 0.f);
}

__global__ void x_kernel(const float* __restrict__ hidden_W, const float* __restrict__ hidden_b,
                         float* __restrict__ vec) {
    int j = blockIdx.x;
    const float* r = hidden_W + (size_t)j * 1536;
    const float* joint = vec;
    float s = 0.f;
    for (int k = threadIdx.x; k < 1536; k += 256) s += r[k] * joint[k];
    s = blockReduceSum256(s);
    if (threadIdx.x == 0) vec[OFF_X + j] = fmaxf(s + hidden_b[j], 0.f);
}

__global__ void out_kernel(const float* __restrict__ vec,
                           const float* __restrict__ critic_W, const float* __restrict__ critic_b,
                           const float* __restrict__ actor_W, const float* __restrict__ actor_b,
                           float* __restrict__ out) {
    const float* xv = vec + OFF_X;
    int w = threadIdx.x >> 6, l = threadIdx.x & 63;
    if (w >= 7) return;
    const float* row = (w == 0) ? critic_W : actor_W + (size_t)(w - 1) * 512;
    float s = 0.f;
    for (int q = l; q < 512; q += 64) s += xv[q] * row[q];
    #pragma unroll
    for (int o = 32; o > 0; o >>= 1) s += __shfl_down(s, o, 64);
    if (l == 0) out[w] = s + ((w == 0) ? critic_b[0] : actor_b[w - 1]);
}

// ---------------- convert kernels (fast path) ----------------
__global__ void cvt_hi_kernel(const float* __restrict__ src, unsigned short* __restrict__ hi) {
    size_t i = (size_t)blockIdx.x * 256 + threadIdx.x;   // one float4 each
    float4 v = ((const float4*)src)[i];
    u16x4 h; h[0] = f2bh(v.x); h[1] = f2bh(v.y); h[2] = f2bh(v.z); h[3] = f2bh(v.w);
    *(u16x4*)(hi + i * 4) = h;
}

__global__ void cvt_split_kernel(const float* __restrict__ src, int R, int C, int Cp,
                                 unsigned short* __restrict__ hi, unsigned short* __restrict__ lo) {
    size_t i = (size_t)blockIdx.x * 256 + threadIdx.x;
    if (i >= (size_t)R * Cp) return;
    int r = (int)(i / Cp), c = (int)(i % Cp);
    float v = (c < C) ? src[(size_t)r * C + c] : 0.f;
    unsigned short h = f2bh(v);
    hi[i] = h;
    lo[i] = f2bh(v - bh2f(h));
}

// src f32 [K,N] -> hiT/loT [N,K]
__global__ void cvt_splitT_kernel(const float* __restrict__ src, int K, int N,
                                  unsigned short* __restrict__ hiT, unsigned short* __restrict__ loT) {
    size_t i = (size_t)blockIdx.x * 256 + threadIdx.x;
    if (i >= (size_t)N * K) return;
    int n = (int)(i / K), k = (int)(i % K);
    float v = src[(size_t)k * N + n];
    unsigned short h = f2bh(v);
    hiT[i] = h;
    loT[i] = f2bh(v - bh2f(h));
}

// ---------------- MFMA split-bf16 GEMM ----------------
// C[M,N] = A[M,K] @ B^T[N,K]^T ; A,B given as bf16 hi(/lo) with K-contiguous rows.
// products: Ah*Bh + Ah*Bl (+ Al*Bh if SPLIT_A)
// WMODE: 0 = f32 C[m][n] (ldc=N); 1 = split bf16 C[m][n] (ldc=N); 2 = split bf16 C^T[n][m] (ldc=M)
template<int SPLIT_A, int WMODE, int RELU>
__global__ __launch_bounds__(256) void mfma_gemm(
    const unsigned short* __restrict__ Ah, const unsigned short* __restrict__ Al,
    const unsigned short* __restrict__ Bh, const unsigned short* __restrict__ Bl,
    int M, int N, int K, int lda, int ldb,
    float* __restrict__ Cf, unsigned short* __restrict__ Ch, unsigned short* __restrict__ Cl,
    int ldc, const float* __restrict__ bias)
{
    constexpr int NMAT = SPLIT_A ? 4 : 3;   // 0=A_hi, 1=B_hi, 2=B_lo, 3=A_lo
    __shared__ unsigned short lds[2][NMAT][128 * 32];

    const int t = threadIdx.x;
    const int w = t >> 6, l = t & 63;
    const int r = l & 15, g = l >> 4;
    const int wr = (w >> 1) * 64, wc = (w & 1) * 64;
    const int row0 = blockIdx.y * 128, col0 = blockIdx.x * 128;

    f32x4 acc[4][4];
    #pragma unroll
    for (int a = 0; a < 4; a++)
        #pragma unroll
        for (int b = 0; b < 4; b++) acc[a][b] = (f32x4){0.f, 0.f, 0.f, 0.f};

    auto stage_one = [&](const unsigned short* src, int ld, int r0, int k0, unsigned short* tile) {
        #pragma unroll
        for (int i = 0; i < 2; i++) {
            int c = i * 256 + t;
            int row = c >> 2;
            int gg = (c & 3) ^ ((row >> 1) & 3);
            const unsigned short* gp = src + (size_t)(r0 + row) * ld + (k0 + gg * 8);
            unsigned short* lp = tile + (size_t)(i * 256 + (t & ~63)) * 8;
            gload16(gp, lp);
        }
    };
    auto stage = [&](int buf, int k0) {
        stage_one(Ah, lda, row0, k0, &lds[buf][0][0]);
        stage_one(Bh, ldb, col0, k0, &lds[buf][1][0]);
        stage_one(Bl, ldb, col0, k0, &lds[buf][2][0]);
        if constexpr (SPLIT_A) stage_one(Al, lda, row0, k0, &lds[buf][NMAT - 1][0]);
    };
    auto rf = [&](const unsigned short* tile, int row) -> s16x8 {
        int byte = row * 64 + ((g ^ ((row >> 1) & 3)) << 4);
        return *(const s16x8*)((const char*)tile + byte);
    };

    stage(0, 0);
    asm volatile("s_waitcnt vmcnt(0)" ::: "memory");
    __builtin_amdgcn_s_barrier();

    int cur = 0;
    for (int kt = 0; kt < K; kt += 32) {
        if (kt + 32 < K) stage(cur ^ 1, kt + 32);

        s16x8 ah[4], bh[4], bl[4], al[4];
        #pragma unroll
        for (int f = 0; f < 4; f++) {
            ah[f] = rf(&lds[cur][0][0], wr + f * 16 + r);
            bh[f] = rf(&lds[cur][1][0], wc + f * 16 + r);
            bl[f] = rf(&lds[cur][2][0], wc + f * 16 + r);
            if constexpr (SPLIT_A) al[f] = rf(&lds[cur][NMAT - 1][0], wr + f * 16 + r);
        }
        #pragma unroll
        for (int fm = 0; fm < 4; fm++)
            #pragma unroll
            for (int fn = 0; fn < 4; fn++) {
                acc[fm][fn] = MF(ah[fm], bh[fn], acc[fm][fn]);
                acc[fm][fn] = MF(ah[fm], bl[fn], acc[fm][fn]);
                if constexpr (SPLIT_A) acc[fm][fn] = MF(al[fm], bh[fn], acc[fm][fn]);
            }
        asm volatile("s_waitcnt vmcnt(0)" ::: "memory");
        __builtin_amdgcn_s_barrier();
        cur ^= 1;
    }

    // epilogue: C/D layout col = lane&15 (=r), row = 4*(lane>>4)+i (=4g+i)  [m89-verified]
    #pragma unroll
    for (int fn = 0; fn < 4; fn++) {
        int n = col0 + wc + fn * 16 + r;
        float bn = bias ? bias[n] : 0.f;
        #pragma unroll
        for (int fm = 0; fm < 4; fm++) {
            int m0 = row0 + wr + fm * 16 + g * 4;
            f32x4 v = acc[fm][fn];
            if constexpr (WMODE == 2) {
                u16x4 hv, lv;
                #pragma unroll
                for (int i = 0; i < 4; i++) {
                    float x = v[i] + bn;
                    if (RELU) x = fmaxf(x, 0.f);
                    unsigned short h = f2bh(x);
                    hv[i] = h; lv[i] = f2bh(x - bh2f(h));
                }
                *(u16x4*)(Ch + (size_t)n * ldc + m0) = hv;
                *(u16x4*)(Cl + (size_t)n * ldc + m0) = lv;
            } else {
                #pragma unroll
                for (int i = 0; i < 4; i++) {
                    float x = v[i] + bn;
                    if (RELU) x = fmaxf(x, 0.f);
                    int m = m0 + i;
                    if constexpr (WMODE == 0) {
                        Cf[(size_t)m * ldc + n] = x;
                    } else {
                        unsigned short h = f2bh(x);
                        Ch[(size_t)m * ldc + n] = h;
                        Cl[(size_t)m * ldc + n] = f2bh(x - bh2f(h));
                    }
                }
            }
        }
    }
}

// ---------------- fallback f32 tiled GEMM (round-1, proven) ----------------
template<int TRANSB>
__global__ __launch_bounds__(256) void gemm_f32_128(
    const float* __restrict__ A, const float* __restrict__ B, float* __restrict__ C,
    int M, int N, int K, int lda, int ldb,
    const float* __restrict__ bias, const float* __restrict__ vrow, int do_relu)
{
    constexpr int BM = 128, BN = 128, BK = 16;
    __shared__ float As[BK][BM + 4];
    __shared__ float Bs[BK][BN + 4];
    const int t = threadIdx.x;
    const int w = t >> 6, l = t & 63;
    const int cx = (w & 1) * 8 + (l & 7);
    const int cy = (w >> 1) * 8 + (l >> 3);
    const int row0 = blockIdx.y * BM;
    const int col0 = blockIdx.x * BN;

    float acc[8][8];
    #pragma unroll
    for (int i = 0; i < 8; i++)
        #pragma unroll
        for (int j = 0; j < 8; j++) acc[i][j] = 0.f;

    const int ka = t & 15;
    const int ma = t >> 4;

    for (int k0 = 0; k0 < K; k0 += BK) {
        #pragma unroll
        for (int i = 0; i < 8; i++) {
            int m = ma + i * 16;
            int gk = k0 + ka;
            float v = 0.f;
            if (gk < K) v = A[(size_t)(row0 + m) * lda + gk];
            As[ka][m] = v;
        }
        if (TRANSB) {
            #pragma unroll
            for (int i = 0; i < 8; i++) {
                int n = ma + i * 16;
                int gk = k0 + ka;
                float v = 0.f;
                if (gk < K) v = B[(size_t)(col0 + n) * ldb + gk];
                Bs[ka][n] = v;
            }
        } else {
            const int nb = t & 127;
            const int kb = t >> 7;
            #pragma unroll
            for (int i = 0; i < 8; i++) {
                int kk = kb + i * 2;
                int gk = k0 + kk;
                float v = 0.f;
                if (gk < K) v = B[(size_t)gk * ldb + col0 + nb];
                Bs[kk][nb] = v;
            }
        }
        __syncthreads();
        #pragma unroll
        for (int kk = 0; kk < BK; kk++) {
            float a[8], bb[8];
            *(float4*)&a[0]  = *(const float4*)&As[kk][cy * 8];
            *(float4*)&a[4]  = *(const float4*)&As[kk][cy * 8 + 4];
            *(float4*)&bb[0] = *(const float4*)&Bs[kk][cx * 8];
            *(float4*)&bb[4] = *(const float4*)&Bs[kk][cx * 8 + 4];
            #pragma unroll
            for (int i = 0; i < 8; i++)
                #pragma unroll
                for (int j = 0; j < 8; j++)
                    acc[i][j] = fmaf(a[i], bb[j], acc[i][j]);
        }
        __syncthreads();
    }

    #pragma unroll
    for (int i = 0; i < 8; i++) {
        int r = row0 + cy * 8 + i;
        float vv[8];
        #pragma unroll
        for (int j = 0; j < 8; j++) {
            int c = col0 + cx * 8 + j;
            float v = acc[i][j];
            if (vrow) v += vrow[c];
            if (bias) v += bias[c];
            if (do_relu) v = fmaxf(v, 0.f);
            vv[j] = v;
        }
        float* cp = C + (size_t)r * N + col0 + cx * 8;
        *(float4*)cp       = *(float4*)&vv[0];
        *(float4*)(cp + 4) = *(float4*)&vv[4];
    }
}

// ---------------- host launcher ----------------
extern "C" void kernel_launch(void* const* d_in, const int* in_sizes, int n_in,
                              void* d_out, int out_size, void* d_ws, size_t ws_size,
                              hipStream_t stream) {
    const float* frames     = (const float*)d_in[0];
    const float* scores     = (const float*)d_in[1];
    const float* word_embed = (const float*)d_in[2];
    const float* all_embeds = (const float*)d_in[3];
    const float* adj        = (const float*)d_in[4];
    const float* visual_W   = (const float*)d_in[5];
    const float* visual_b   = (const float*)d_in[6];
    const float* semantic_W = (const float*)d_in[7];
    const float* semantic_b = (const float*)d_in[8];
    const float* score_W    = (const float*)d_in[9];
    const float* score_b    = (const float*)d_in[10];
    const float* gc1_W      = (const float*)d_in[11];
    const float* gc1_b      = (const float*)d_in[12];
    const float* gc2_W      = (const float*)d_in[13];
    const float* gc2_b      = (const float*)d_in[14];
    const float* gc3_W      = (const float*)d_in[15];
    const float* gc3_b      = (const float*)d_in[16];
    const float* gcn512_W   = (const float*)d_in[17];
    const float* gcn512_b   = (const float*)d_in[18];
    const float* hidden_W   = (const float*)d_in[19];
    const float* hidden_b   = (const float*)d_in[20];
    const float* critic_W   = (const float*)d_in[21];
    const float* critic_b   = (const float*)d_in[22];
    const float* actor_W    = (const float*)d_in[23];
    const float* actor_b    = (const float*)d_in[24];

    float* out = (float*)d_out;

    if (ws_size >= FAST_WS) {
        // ---------------- fast MFMA path ----------------
        char* wsb = (char*)d_ws;
        unsigned short* adj_h = (unsigned short*)(wsb + B_ADJH);
        unsigned short* emb_h = (unsigned short*)(wsb + B_EMB_H);
        unsigned short* emb_l = (unsigned short*)(wsb + B_EMB_L);
        unsigned short* sw_h  = (unsigned short*)(wsb + B_SW_H);
        unsigned short* sw_l  = (unsigned short*)(wsb + B_SW_L);
        unsigned short* w1t_h = (unsigned short*)(wsb + B_W1T_H);
        unsigned short* w1t_l = (unsigned short*)(wsb + B_W1T_L);
        unsigned short* w2t_h = (unsigned short*)(wsb + B_W2T_H);
        unsigned short* w2t_l = (unsigned short*)(wsb + B_W2T_L);
        unsigned short* em_h  = (unsigned short*)(wsb + B_EM_H);
        unsigned short* em_l  = (unsigned short*)(wsb + B_EM_L);
        unsigned short* y1t_h = (unsigned short*)(wsb + B_Y1T_H);
        unsigned short* y1t_l = (unsigned short*)(wsb + B_Y1T_L);
        unsigned short* h1_h  = (unsigned short*)(wsb + B_H1_H);
        unsigned short* h1_l  = (unsigned short*)(wsb + B_H1_L);
        float* H2f = (float*)(wsb + B_H2F);
        float* vec = (float*)(wsb + B_VEC);

        // converts
        cvt_hi_kernel<<<16384, 256, 0, stream>>>(adj, adj_h);
        cvt_split_kernel<<<5120, 256, 0, stream>>>(all_embeds, 4096, 300, 320, emb_h, emb_l);
        cvt_split_kernel<<<640, 256, 0, stream>>>(semantic_W, 512, 300, 320, sw_h, sw_l);
        cvt_splitT_kernel<<<2048, 256, 0, stream>>>(gc1_W + (size_t)512 * 1024, 512, 1024, w1t_h, w1t_l);
        cvt_splitT_kernel<<<4096, 256, 0, stream>>>(gc2_W, 1024, 1024, w2t_h, w2t_l);
        // small vectors
        vec3_kernel<<<1536, 256, 0, stream>>>(frames, scores, word_embed,
                                              visual_W, visual_b, semantic_W, semantic_b,
                                              score_W, score_b, vec);
        vrow_kernel<<<4, 256, 0, stream>>>(gc1_W, vec);
        // #3: em = relu(all_embeds @ semantic_W^T + b)   [4096,512] K=320, split x split
        mfma_gemm<1, 1, 1><<<dim3(4, 32), 256, 0, stream>>>(
            emb_h, emb_l, sw_h, sw_l, 4096, 512, 320, 320, 320,
            nullptr, em_h, em_l, 512, semantic_b);
        // #4: Y1^T = (em @ gc1_W[512:] + vrow)^T  [1024,4096], K=512
        mfma_gemm<1, 2, 0><<<dim3(8, 32), 256, 0, stream>>>(
            em_h, em_l, w1t_h, w1t_l, 4096, 1024, 512, 512, 512,
            nullptr, y1t_h, y1t_l, 4096, vec + OFF_VROW);
        // #5: H1 = relu(adj @ Y1 + gc1_b)  [4096,1024], K=4096 (adj hi-only)
        mfma_gemm<0, 1, 1><<<dim3(8, 32), 256, 0, stream>>>(
            adj_h, nullptr, y1t_h, y1t_l, 4096, 1024, 4096, 4096, 4096,
            nullptr, h1_h, h1_l, 1024, gc1_b);
        // #6: Y2^T = (H1 @ gc2_W)^T  [1024,4096], K=1024  (overwrites Y1T slots)
        mfma_gemm<1, 2, 0><<<dim3(8, 32), 256, 0, stream>>>(
            h1_h, h1_l, w2t_h, w2t_l, 4096, 1024, 1024, 1024, 1024,
            nullptr, y1t_h, y1t_l, 4096, nullptr);
        // #7: H2 = relu(adj @ Y2 + gc2_b)  f32 [4096,1024], K=4096
        mfma_gemm<0, 0, 1><<<dim3(8, 32), 256, 0, stream>>>(
            adj_h, nullptr, y1t_h, y1t_l, 4096, 1024, 4096, 4096, 4096,
            H2f, nullptr, nullptr, 1024, gc2_b);
        // tail
        y3_kernel<<<4096, 256, 0, stream>>>(H2f, gc3_W, vec);
        h3_kernel<<<4096, 256, 0, stream>>>(adj, gc3_b, vec);
        gcn_kernel<<<512, 256, 0, stream>>>(gcn512_W, gcn512_b, vec);
        x_kernel<<<512, 256, 0, stream>>>(hidden_W, hidden_b, vec);
        out_kernel<<<1, 512, 0, stream>>>(vec, critic_W, critic_b, actor_W, actor_b, out);
    } else {
        // ---------------- fallback f32 path (round-1, proven within 50.4 MB) ----------------
        float* ws = (float*)d_ws;
        float* em = ws + OFF_BUF0;
        float* Y1 = ws + OFF_BUF1;
        float* H1 = ws + OFF_BUF2;
        float* Y2 = ws + OFF_BUF1;
        float* H2 = ws + OFF_BUF0;

        vec3_kernel<<<1536, 256, 0, stream>>>(frames, scores, word_embed,
                                              visual_W, visual_b, semantic_W, semantic_b,
                                              score_W, score_b, ws);
        vrow_kernel<<<4, 256, 0, stream>>>(gc1_W, ws);
        gemm_f32_128<1><<<dim3(512 / 128, 4096 / 128), 256, 0, stream>>>(
            all_embeds, semantic_W, em, 4096, 512, 300, 300, 300, semantic_b, nullptr, 1);
        gemm_f32_128<0><<<dim3(1024 / 128, 4096 / 128), 256, 0, stream>>>(
            em, gc1_W + (size_t)512 * 1024, Y1, 4096, 1024, 512, 512, 1024,
            nullptr, ws + OFF_VROW, 0);
        gemm_f32_128<0><<<dim3(1024 / 128, 4096 / 128), 256, 0, stream>>>(
            adj, Y1, H1, 4096, 1024, 4096, 4096, 1024, gc1_b, nullptr, 1);
        gemm_f32_128<0><<<dim3(1024 / 128, 4096 / 128), 256, 0, stream>>>(
            H1, gc2_W, Y2, 4096, 1024, 1024, 1024, 1024, nullptr, nullptr, 0);
        gemm_f32_128<0><<<dim3(1024 / 128, 4096 / 128), 256, 0, stream>>>(
            adj, Y2, H2, 4096, 1024, 4096, 4096, 1024, gc2_b, nullptr, 1);
        y3_kernel<<<4096, 256, 0, stream>>>(H2, gc3_W, ws);
        h3_kernel<<<4096, 256, 0, stream>>>(adj, gc3_b, ws);
        gcn_kernel<<<512, 256, 0, stream>>>(gcn512_W, gcn512_b, ws);
        x_kernel<<<512, 256, 0, stream>>>(hidden_W, hidden_b, ws);
        out_kernel<<<1, 512, 0, stream>>>(ws, critic_W, critic_b, actor_W, actor_b, out);
    }

    (void)in_sizes; (void)n_in; (void)out_size;
}

// Round 3
// 236.583 us; speedup vs baseline: 11.2620x; 1.6664x over previous
//
#include <hip/hip_runtime.h>
#include <cstddef>
#include <cstdint>

typedef short  s16x8 __attribute__((ext_vector_type(8)));
typedef float  f32x4 __attribute__((ext_vector_type(4)));
typedef unsigned short u16x4 __attribute__((ext_vector_type(4)));

typedef __attribute__((address_space(1))) const void gas_void;
typedef __attribute__((address_space(3))) void las_void;

// ---------------- bf16 helpers ----------------
__device__ __forceinline__ unsigned short f2bh(float x) {
    union { float f; unsigned int u; } c; c.f = x;
    unsigned int r = c.u + 0x7fffu + ((c.u >> 16) & 1u);
    return (unsigned short)(r >> 16);
}
__device__ __forceinline__ float bh2f(unsigned short h) {
    union { unsigned int u; float f; } c; c.u = ((unsigned int)h) << 16;
    return c.f;
}
__device__ __forceinline__ f32x4 MF(s16x8 a, s16x8 b, f32x4 c) {
    return __builtin_amdgcn_mfma_f32_16x16x32_bf16(a, b, c, 0, 0, 0);
}
__device__ __forceinline__ void gload16(const unsigned short* g, unsigned short* l) {
    __builtin_amdgcn_global_load_lds((gas_void*)g, (las_void*)l, 16, 0, 0);
}

// ---------------- vec region offsets (floats) ----------------
static constexpr size_t OFF_VIS  = 0;
static constexpr size_t OFF_SEM  = 512;
static constexpr size_t OFF_GCN  = 1024;
static constexpr size_t OFF_S512 = 1536;
static constexpr size_t OFF_VROW = 2048;
static constexpr size_t OFF_X    = 3072;
static constexpr size_t OFF_Y3   = 4096;
static constexpr size_t OFF_H3   = 8192;
// fallback big buffers (floats, absolute in ws)
static constexpr size_t OFF_BUF0 = 16384;
static constexpr size_t OFF_BUF1 = OFF_BUF0 + 4194304;
static constexpr size_t OFF_BUF2 = OFF_BUF1 + 4194304;

// ---------------- fast-path ws layout (bytes) ----------------
static constexpr size_t F_ADJH  = 0;                         // 4096*4096*2
static constexpr size_t F_EMB_H = F_ADJH + 33554432;         // 4096*320*2
static constexpr size_t F_EMB_L = F_EMB_H + 2621440;
static constexpr size_t F_SW_H  = F_EMB_L + 2621440;         // 512*320*2
static constexpr size_t F_SW_L  = F_SW_H + 327680;
static constexpr size_t F_W1T_H = F_SW_L + 327680;           // 1024*512*2
static constexpr size_t F_W1T_L = F_W1T_H + 1048576;
static constexpr size_t F_W2T_H = F_W1T_L + 1048576;         // 1024*1024*2
static constexpr size_t F_EM_H  = F_W2T_H + 2097152;         // 4096*512*2
static constexpr size_t F_EM_L  = F_EM_H + 4194304;
static constexpr size_t F_Y1T   = F_EM_L + 4194304;          // 1024*4096*2 (also y2t)
static constexpr size_t F_H1    = F_Y1T + 8388608;           // 4096*1024*2
static constexpr size_t F_H2F   = F_H1 + 8388608;            // 4096*1024*4
static constexpr size_t F_VEC   = F_H2F + 16777216;          // 12288 floats
static constexpr size_t FAST_WS = F_VEC + 49152;             // ~85.6 MB

// ---------------- block reduction ----------------
__device__ inline float blockReduceSum256(float v) {
    #pragma unroll
    for (int o = 32; o > 0; o >>= 1) v += __shfl_down(v, o, 64);
    __shared__ float red[4];
    int w = threadIdx.x >> 6;
    if ((threadIdx.x & 63) == 0) red[w] = v;
    __syncthreads();
    if (threadIdx.x == 0) v = red[0] + red[1] + red[2] + red[3];
    return v;
}

// ---------------- small kernels ----------------
__global__ void vec3_kernel(const float* __restrict__ frames,
                            const float* __restrict__ scores,
                            const float* __restrict__ word_embed,
                            const float* __restrict__ visual_W, const float* __restrict__ visual_b,
                            const float* __restrict__ semantic_W, const float* __restrict__ semantic_b,
                            const float* __restrict__ score_W, const float* __restrict__ score_b,
                            float* __restrict__ vec) {
    int b = blockIdx.x;
    const float* x; const float* W; const float* bias; float* out; int K; int row;
    if (b < 512)       { row = b;        x = frames;     W = visual_W;   bias = visual_b;   out = vec + OFF_VIS;  K = 8192; }
    else if (b < 1024) { row = b - 512;  x = word_embed; W = semantic_W; bias = semantic_b; out = vec + OFF_SEM;  K = 300;  }
    else               { row = b - 1024; x = scores;     W = score_W;    bias = score_b;    out = vec + OFF_S512; K = 1000; }
    const float* wr = W + (size_t)row * K;
    float s = 0.f;
    for (int k = threadIdx.x; k < K; k += 256) s += wr[k] * x[k];
    s = blockReduceSum256(s);
    if (threadIdx.x == 0) out[row] = fmaxf(s + bias[row], 0.f);
}

__global__ void vrow_kernel(const float* __restrict__ gc1_W, float* __restrict__ vec) {
    int j = blockIdx.x * 256 + threadIdx.x;
    const float* s512 = vec + OFF_S512;
    float s = 0.f;
    for (int k = 0; k < 512; k++) s += s512[k] * gc1_W[(size_t)k * 1024 + j];
    vec[OFF_VROW + j] = s;
}

__global__ void y3_kernel(const float* __restrict__ H2, const float* __restrict__ gc3_W,
                          float* __restrict__ vec) {
    int i = blockIdx.x;
    const float* r = H2 + (size_t)i * 1024;
    float s = 0.f;
    for (int k = threadIdx.x; k < 1024; k += 256) s += r[k] * gc3_W[k];
    s = blockReduceSum256(s);
    if (threadIdx.x == 0) vec[OFF_Y3 + i] = s;
}

// h3 from bf16 adj
__global__ void h3b_kernel(const unsigned short* __restrict__ adj_h,
                           const float* __restrict__ gc3_b, float* __restrict__ vec) {
    int i = blockIdx.x;
    const u16x4* rp = (const u16x4*)(adj_h + (size_t)i * 4096);
    const float* y3 = vec + OFF_Y3;
    float s = 0.f;
    for (int c = threadIdx.x; c < 1024; c += 256) {
        u16x4 v = rp[c];
        int k0 = c * 4;
        s += bh2f(v[0]) * y3[k0] + bh2f(v[1]) * y3[k0 + 1]
           + bh2f(v[2]) * y3[k0 + 2] + bh2f(v[3]) * y3[k0 + 3];
    }
    s = blockReduceSum256(s);
    if (threadIdx.x == 0) vec[OFF_H3 + i] = fmaxf(s + gc3_b[0], 0.f);
}

__global__ void h3_kernel(const float* __restrict__ adj, const float* __restrict__ gc3_b,
                          float* __restrict__ vec) {
    int i = blockIdx.x;
    const float* r = adj + (size_t)i * 4096;
    const float* y3 = vec + OFF_Y3;
    float s = 0.f;
    for (int k = threadIdx.x; k < 4096; k += 256) s += r[k] * y3[k];
    s = blockReduceSum256(s);
    if (threadIdx.x == 0) vec[OFF_H3 + i] = fmaxf(s + gc3_b[0], 0.f);
}

__global__ void gcn_kernel(const float* __restrict__ gcn512_W, const float* __restrict__ gcn512_b,
                           float* __restrict__ vec) {
    int j = blockIdx.x;
    const float* r = gcn512_W + (size_t)j * 4096;
    const float* h3 = vec + OFF_H3;
    float s = 0.f;
    for (int k = threadIdx.x; k < 4096; k += 256) s += r[k] * h3[k];
    s = blockReduceSum256(s);
    if (threadIdx.x == 0) vec[OFF_GCN + j] = fmaxf(s + gcn512_b[j], 0.f);
}

__global__ void x_kernel(const float* __restrict__ hidden_W, const float* __restrict__ hidden_b,
                         float* __restrict__ vec) {
    int j = blockIdx.x;
    const float* r = hidden_W + (size_t)j * 1536;
    const float* joint = vec;
    float s = 0.f;
    for (int k = threadIdx.x; k < 1536; k += 256) s += r[k] * joint[k];
    s = blockReduceSum256(s);
    if (threadIdx.x == 0) vec[OFF_X + j] = fmaxf(s + hidden_b[j], 0.f);
}

__global__ void out_kernel(const float* __restrict__ vec,
                           const float* __restrict__ critic_W, const float* __restrict__ critic_b,
                           const float* __restrict__ actor_W, const float* __restrict__ actor_b,
                           float* __restrict__ out) {
    const float* xv = vec + OFF_X;
    int w = threadIdx.x >> 6, l = threadIdx.x & 63;
    if (w >= 7) return;
    const float* row = (w == 0) ? critic_W : actor_W + (size_t)(w - 1) * 512;
    float s = 0.f;
    for (int q = l; q < 512; q += 64) s += xv[q] * row[q];
    #pragma unroll
    for (int o = 32; o > 0; o >>= 1) s += __shfl_down(s, o, 64);
    if (l == 0) out[w] = s + ((w == 0) ? critic_b[0] : actor_b[w - 1]);
}

// ---------------- convert kernels ----------------
__global__ void cvt_hi_kernel(const float* __restrict__ src, unsigned short* __restrict__ hi) {
    size_t i = (size_t)blockIdx.x * 256 + threadIdx.x;
    float4 v = ((const float4*)src)[i];
    u16x4 h; h[0] = f2bh(v.x); h[1] = f2bh(v.y); h[2] = f2bh(v.z); h[3] = f2bh(v.w);
    *(u16x4*)(hi + i * 4) = h;
}

__global__ void cvt_split_kernel(const float* __restrict__ src, int R, int C, int Cp,
                                 unsigned short* __restrict__ hi, unsigned short* __restrict__ lo) {
    size_t i = (size_t)blockIdx.x * 256 + threadIdx.x;
    if (i >= (size_t)R * Cp) return;
    int r = (int)(i / Cp), c = (int)(i % Cp);
    float v = (c < C) ? src[(size_t)r * C + c] : 0.f;
    unsigned short h = f2bh(v);
    hi[i] = h;
    lo[i] = f2bh(v - bh2f(h));
}

// LDS-tiled transpose convert: src f32 [K,N] -> hiT(/loT) [N,K]
__global__ void cvt_T_kernel(const float* __restrict__ src, int K, int N,
                             unsigned short* __restrict__ hiT, unsigned short* __restrict__ loT) {
    __shared__ float tile[32][33];
    int kb = blockIdx.x * 32, nb = blockIdx.y * 32;
    int tx = threadIdx.x & 31, ty = threadIdx.x >> 5;   // ty 0..7
    #pragma unroll
    for (int i = 0; i < 32; i += 8)
        tile[ty + i][tx] = src[(size_t)(kb + ty + i) * N + nb + tx];
    __syncthreads();
    #pragma unroll
    for (int i = 0; i < 32; i += 8) {
        int n = nb + ty + i, k = kb + tx;
        float v = tile[tx][ty + i];
        unsigned short h = f2bh(v);
        hiT[(size_t)n * K + k] = h;
        if (loT) loT[(size_t)n * K + k] = f2bh(v - bh2f(h));
    }
}

// ---------------- MFMA bf16 GEMM, 128x64 tile, ring-3 counted-vmcnt pipeline ----------------
// C[M,N] = A[M,K] @ B^T ; A,B bf16, K-contiguous rows (NT).
// PROD: 1 = Ah*Bh ; 2 = +Ah*Bl ; 3 = +Al*Bh
// WMODE: 0 f32 C[m][n]; 1 hi+lo C[m][n]; 3 hi C[m][n]; 4 hi C^T[n][m] (ldc=M)
template<int PROD, int WMODE, int RELU>
__global__ __launch_bounds__(256) void mfma_gemm(
    const unsigned short* __restrict__ Ah, const unsigned short* __restrict__ Al,
    const unsigned short* __restrict__ Bh, const unsigned short* __restrict__ Bl,
    int K, int lda, int ldb,
    float* __restrict__ Cf, unsigned short* __restrict__ Ch, unsigned short* __restrict__ Cl,
    int ldc, const float* __restrict__ bias)
{
    // ring slot (ushorts): Ah[0..4095] Bh[4096..6143] (Bl[6144..8191]) (Al[8192..12287])
    constexpr int SLOT = (PROD == 1) ? 6144 : (PROD == 2) ? 8192 : 12288;
    __shared__ unsigned short lds[3 * SLOT];

    const int t = threadIdx.x;
    const int w = t >> 6, l = t & 63;
    const int r = l & 15, g4 = l >> 4;
    const int wr = (w >> 1) * 64;   // wave rows (of 128)
    const int wc = (w & 1) * 32;    // wave cols (of 64)

    // XCD-aware bijective swizzle (nwg is always a multiple of 8 here)
    const int gx = gridDim.x;
    const int nwg = gx * gridDim.y;
    int flat = blockIdx.y * gx + blockIdx.x;
    int q = nwg >> 3;
    int swz = (flat & 7) * q + (flat >> 3);
    const int col0 = (swz % gx) * 64;
    const int row0 = (swz / gx) * 128;

    f32x4 acc[4][2];
    #pragma unroll
    for (int a = 0; a < 4; a++)
        #pragma unroll
        for (int b = 0; b < 2; b++) acc[a][b] = (f32x4){0.f, 0.f, 0.f, 0.f};

    auto stage = [&](int slot, int k0) {
        unsigned short* base = lds + slot * SLOT;
        // A_h: 128x32 = 512 16B-chunks
        #pragma unroll
        for (int i = 0; i < 2; i++) {
            int c = i * 256 + t;
            int row = c >> 2;
            int gg = (c & 3) ^ ((row >> 1) & 3);
            gload16(Ah + (size_t)(row0 + row) * lda + (k0 + gg * 8),
                    base + (size_t)(i * 256 + (t & ~63)) * 8);
        }
        // B_h: 64x32 = 256 chunks
        {
            int row = t >> 2;
            int gg = (t & 3) ^ ((row >> 1) & 3);
            gload16(Bh + (size_t)(col0 + row) * ldb + (k0 + gg * 8),
                    base + 4096 + (size_t)(t & ~63) * 8);
        }
        if constexpr (PROD >= 2) {
            int row = t >> 2;
            int gg = (t & 3) ^ ((row >> 1) & 3);
            gload16(Bl + (size_t)(col0 + row) * ldb + (k0 + gg * 8),
                    base + 6144 + (size_t)(t & ~63) * 8);
        }
        if constexpr (PROD >= 3) {
            #pragma unroll
            for (int i = 0; i < 2; i++) {
                int c = i * 256 + t;
                int row = c >> 2;
                int gg = (c & 3) ^ ((row >> 1) & 3);
                gload16(Al + (size_t)(row0 + row) * lda + (k0 + gg * 8),
                        base + 8192 + (size_t)(i * 256 + (t & ~63)) * 8);
            }
        }
    };
    auto rf = [&](const unsigned short* tilep, int row) -> s16x8 {
        int byte = row * 64 + ((g4 ^ ((row >> 1) & 3)) << 4);
        return *(const s16x8*)((const char*)tilep + byte);
    };

    const int T = K >> 5;
    stage(0, 0);
    stage(1, 32);

    for (int tt = 0; tt < T; ++tt) {
        __builtin_amdgcn_s_barrier();                 // all waves done computing tt-1
        if (tt + 2 < T) {
            stage((tt + 2) % 3, (tt + 2) * 32);       // overwrite slot computed at tt-1
            if constexpr (PROD == 1)      asm volatile("s_waitcnt vmcnt(6)" ::: "memory");
            else if constexpr (PROD == 2) asm volatile("s_waitcnt vmcnt(8)" ::: "memory");
            else                          asm volatile("s_waitcnt vmcnt(12)" ::: "memory");
        } else if (tt + 1 < T) {
            if constexpr (PROD == 1)      asm volatile("s_waitcnt vmcnt(3)" ::: "memory");
            else if constexpr (PROD == 2) asm volatile("s_waitcnt vmcnt(4)" ::: "memory");
            else                          asm volatile("s_waitcnt vmcnt(6)" ::: "memory");
        } else {
            asm volatile("s_waitcnt vmcnt(0)" ::: "memory");
        }
        __builtin_amdgcn_s_barrier();                 // slot tt staged for everyone

        const unsigned short* base = lds + (tt % 3) * SLOT;
        s16x8 a[4], b[2], blr[2], alr[4];
        #pragma unroll
        for (int f = 0; f < 4; f++) a[f] = rf(base, wr + f * 16 + r);
        #pragma unroll
        for (int f = 0; f < 2; f++) b[f] = rf(base + 4096, wc + f * 16 + r);
        if constexpr (PROD >= 2) {
            #pragma unroll
            for (int f = 0; f < 2; f++) blr[f] = rf(base + 6144, wc + f * 16 + r);
        }
        if constexpr (PROD >= 3) {
            #pragma unroll
            for (int f = 0; f < 4; f++) alr[f] = rf(base + 8192, wr + f * 16 + r);
        }
        #pragma unroll
        for (int fm = 0; fm < 4; fm++)
            #pragma unroll
            for (int fn = 0; fn < 2; fn++) {
                acc[fm][fn] = MF(a[fm], b[fn], acc[fm][fn]);
                if constexpr (PROD >= 2) acc[fm][fn] = MF(a[fm], blr[fn], acc[fm][fn]);
                if constexpr (PROD >= 3) acc[fm][fn] = MF(alr[fm], b[fn], acc[fm][fn]);
            }
    }

    // epilogue (C/D: col = lane&15, row = 4*(lane>>4)+i — m89-verified)
    #pragma unroll
    for (int fn = 0; fn < 2; fn++) {
        int n = col0 + wc + fn * 16 + r;
        float bn = bias ? bias[n] : 0.f;
        #pragma unroll
        for (int fm = 0; fm < 4; fm++) {
            int m0 = row0 + wr + fm * 16 + g4 * 4;
            f32x4 v = acc[fm][fn];
            if constexpr (WMODE == 4) {
                u16x4 hv;
                #pragma unroll
                for (int i = 0; i < 4; i++) {
                    float x = v[i] + bn;
                    if (RELU) x = fmaxf(x, 0.f);
                    hv[i] = f2bh(x);
                }
                *(u16x4*)(Ch + (size_t)n * ldc + m0) = hv;
            } else {
                #pragma unroll
                for (int i = 0; i < 4; i++) {
                    float x = v[i] + bn;
                    if (RELU) x = fmaxf(x, 0.f);
                    int m = m0 + i;
                    if constexpr (WMODE == 0) {
                        Cf[(size_t)m * ldc + n] = x;
                    } else if constexpr (WMODE == 1) {
                        unsigned short h = f2bh(x);
                        Ch[(size_t)m * ldc + n] = h;
                        Cl[(size_t)m * ldc + n] = f2bh(x - bh2f(h));
                    } else {  // WMODE 3
                        Ch[(size_t)m * ldc + n] = f2bh(x);
                    }
                }
            }
        }
    }
}

// ---------------- fallback f32 tiled GEMM (round-1, proven) ----------------
template<int TRANSB>
__global__ __launch_bounds__(256) void gemm_f32_128(
    const float* __restrict__ A, const float* __restrict__ B, float* __restrict__ C,
    int M, int N, int K, int lda, int ldb,
    const float* __restrict__ bias, const float* __restrict__ vrow, int do_relu)
{
    constexpr int BM = 128, BN = 128, BK = 16;
    __shared__ float As[BK][BM + 4];
    __shared__ float Bs[BK][BN + 4];
    const int t = threadIdx.x;
    const int w = t >> 6, l = t & 63;
    const int cx = (w & 1) * 8 + (l & 7);
    const int cy = (w >> 1) * 8 + (l >> 3);
    const int row0 = blockIdx.y * BM;
    const int col0 = blockIdx.x * BN;

    float acc[8][8];
    #pragma unroll
    for (int i = 0; i < 8; i++)
        #pragma unroll
        for (int j = 0; j < 8; j++) acc[i][j] = 0.f;

    const int ka = t & 15;
    const int ma = t >> 4;

    for (int k0 = 0; k0 < K; k0 += BK) {
        #pragma unroll
        for (int i = 0; i < 8; i++) {
            int m = ma + i * 16;
            int gk = k0 + ka;
            float v = 0.f;
            if (gk < K) v = A[(size_t)(row0 + m) * lda + gk];
            As[ka][m] = v;
        }
        if (TRANSB) {
            #pragma unroll
            for (int i = 0; i < 8; i++) {
                int n = ma + i * 16;
                int gk = k0 + ka;
                float v = 0.f;
                if (gk < K) v = B[(size_t)(col0 + n) * ldb + gk];
                Bs[ka][n] = v;
            }
        } else {
            const int nb = t & 127;
            const int kb = t >> 7;
            #pragma unroll
            for (int i = 0; i < 8; i++) {
                int kk = kb + i * 2;
                int gk = k0 + kk;
                float v = 0.f;
                if (gk < K) v = B[(size_t)gk * ldb + col0 + nb];
                Bs[kk][nb] = v;
            }
        }
        __syncthreads();
        #pragma unroll
        for (int kk = 0; kk < BK; kk++) {
            float a[8], bb[8];
            *(float4*)&a[0]  = *(const float4*)&As[kk][cy * 8];
            *(float4*)&a[4]  = *(const float4*)&As[kk][cy * 8 + 4];
            *(float4*)&bb[0] = *(const float4*)&Bs[kk][cx * 8];
            *(float4*)&bb[4] = *(const float4*)&Bs[kk][cx * 8 + 4];
            #pragma unroll
            for (int i = 0; i < 8; i++)
                #pragma unroll
                for (int j = 0; j < 8; j++)
                    acc[i][j] = fmaf(a[i], bb[j], acc[i][j]);
        }
        __syncthreads();
    }

    #pragma unroll
    for (int i = 0; i < 8; i++) {
        int rr = row0 + cy * 8 + i;
        float vv[8];
        #pragma unroll
        for (int j = 0; j < 8; j++) {
            int c = col0 + cx * 8 + j;
            float v = acc[i][j];
            if (vrow) v += vrow[c];
            if (bias) v += bias[c];
            if (do_relu) v = fmaxf(v, 0.f);
            vv[j] = v;
        }
        float* cp = C + (size_t)rr * N + col0 + cx * 8;
        *(float4*)cp       = *(float4*)&vv[0];
        *(float4*)(cp + 4) = *(float4*)&vv[4];
    }
}

// ---------------- host launcher ----------------
extern "C" void kernel_launch(void* const* d_in, const int* in_sizes, int n_in,
                              void* d_out, int out_size, void* d_ws, size_t ws_size,
                              hipStream_t stream) {
    const float* frames     = (const float*)d_in[0];
    const float* scores     = (const float*)d_in[1];
    const float* word_embed = (const float*)d_in[2];
    const float* all_embeds = (const float*)d_in[3];
    const float* adj        = (const float*)d_in[4];
    const float* visual_W   = (const float*)d_in[5];
    const float* visual_b   = (const float*)d_in[6];
    const float* semantic_W = (const float*)d_in[7];
    const float* semantic_b = (const float*)d_in[8];
    const float* score_W    = (const float*)d_in[9];
    const float* score_b    = (const float*)d_in[10];
    const float* gc1_W      = (const float*)d_in[11];
    const float* gc1_b      = (const float*)d_in[12];
    const float* gc2_W      = (const float*)d_in[13];
    const float* gc2_b      = (const float*)d_in[14];
    const float* gc3_W      = (const float*)d_in[15];
    const float* gc3_b      = (const float*)d_in[16];
    const float* gcn512_W   = (const float*)d_in[17];
    const float* gcn512_b   = (const float*)d_in[18];
    const float* hidden_W   = (const float*)d_in[19];
    const float* hidden_b   = (const float*)d_in[20];
    const float* critic_W   = (const float*)d_in[21];
    const float* critic_b   = (const float*)d_in[22];
    const float* actor_W    = (const float*)d_in[23];
    const float* actor_b    = (const float*)d_in[24];

    float* out = (float*)d_out;

    if (ws_size >= FAST_WS) {
        char* wsb = (char*)d_ws;
        unsigned short* adj_h = (unsigned short*)(wsb + F_ADJH);
        unsigned short* emb_h = (unsigned short*)(wsb + F_EMB_H);
        unsigned short* emb_l = (unsigned short*)(wsb + F_EMB_L);
        unsigned short* sw_h  = (unsigned short*)(wsb + F_SW_H);
        unsigned short* sw_l  = (unsigned short*)(wsb + F_SW_L);
        unsigned short* w1t_h = (unsigned short*)(wsb + F_W1T_H);
        unsigned short* w1t_l = (unsigned short*)(wsb + F_W1T_L);
        unsigned short* w2t_h = (unsigned short*)(wsb + F_W2T_H);
        unsigned short* em_h  = (unsigned short*)(wsb + F_EM_H);
        unsigned short* em_l  = (unsigned short*)(wsb + F_EM_L);
        unsigned short* y1t   = (unsigned short*)(wsb + F_Y1T);   // also y2t
        unsigned short* h1    = (unsigned short*)(wsb + F_H1);
        float*          H2f   = (float*)(wsb + F_H2F);
        float*          vec   = (float*)(wsb + F_VEC);

        // converts
        cvt_hi_kernel<<<16384, 256, 0, stream>>>(adj, adj_h);
        cvt_split_kernel<<<5120, 256, 0, stream>>>(all_embeds, 4096, 300, 320, emb_h, emb_l);
        cvt_split_kernel<<<640, 256, 0, stream>>>(semantic_W, 512, 300, 320, sw_h, sw_l);
        cvt_T_kernel<<<dim3(16, 32), 256, 0, stream>>>(gc1_W + (size_t)512 * 1024, 512, 1024, w1t_h, w1t_l);
        cvt_T_kernel<<<dim3(32, 32), 256, 0, stream>>>(gc2_W, 1024, 1024, w2t_h, nullptr);
        // small vectors
        vec3_kernel<<<1536, 256, 0, stream>>>(frames, scores, word_embed,
                                              visual_W, visual_b, semantic_W, semantic_b,
                                              score_W, score_b, vec);
        vrow_kernel<<<4, 256, 0, stream>>>(gc1_W, vec);
        // #3: em(hi,lo) = relu(emb @ sw^T + b)   [4096,512], K=320
        mfma_gemm<3, 1, 1><<<dim3(8, 32), 256, 0, stream>>>(
            emb_h, emb_l, sw_h, sw_l, 320, 320, 320,
            nullptr, em_h, em_l, 512, semantic_b);
        // #4: y1t = (em @ w1 + vrow)^T  hi [1024,4096], K=512
        mfma_gemm<3, 4, 0><<<dim3(16, 32), 256, 0, stream>>>(
            em_h, em_l, w1t_h, w1t_l, 512, 512, 512,
            nullptr, y1t, nullptr, 4096, vec + OFF_VROW);
        // #5: h1 = relu(adj @ Y1 + b)  hi [4096,1024], K=4096
        mfma_gemm<1, 3, 1><<<dim3(16, 32), 256, 0, stream>>>(
            adj_h, nullptr, y1t, nullptr, 4096, 4096, 4096,
            nullptr, h1, nullptr, 1024, gc1_b);
        // #6: y2t = (h1 @ gc2_W)^T  hi [1024,4096], K=1024  (reuses y1t buffer)
        mfma_gemm<1, 4, 0><<<dim3(16, 32), 256, 0, stream>>>(
            h1, nullptr, w2t_h, nullptr, 1024, 1024, 1024,
            nullptr, y1t, nullptr, 4096, nullptr);
        // #7: H2 = relu(adj @ Y2 + b)  f32 [4096,1024], K=4096
        mfma_gemm<1, 0, 1><<<dim3(16, 32), 256, 0, stream>>>(
            adj_h, nullptr, y1t, nullptr, 4096, 4096, 4096,
            H2f, nullptr, nullptr, 1024, gc2_b);
        // tail
        y3_kernel<<<4096, 256, 0, stream>>>(H2f, gc3_W, vec);
        h3b_kernel<<<4096, 256, 0, stream>>>(adj_h, gc3_b, vec);
        gcn_kernel<<<512, 256, 0, stream>>>(gcn512_W, gcn512_b, vec);
        x_kernel<<<512, 256, 0, stream>>>(hidden_W, hidden_b, vec);
        out_kernel<<<1, 512, 0, stream>>>(vec, critic_W, critic_b, actor_W, actor_b, out);
    } else {
        // fallback f32 path
        float* ws = (float*)d_ws;
        float* em = ws + OFF_BUF0;
        float* Y1 = ws + OFF_BUF1;
        float* H1 = ws + OFF_BUF2;
        float* Y2 = ws + OFF_BUF1;
        float* H2 = ws + OFF_BUF0;

        vec3_kernel<<<1536, 256, 0, stream>>>(frames, scores, word_embed,
                                              visual_W, visual_b, semantic_W, semantic_b,
                                              score_W, score_b, ws);
        vrow_kernel<<<4, 256, 0, stream>>>(gc1_W, ws);
        gemm_f32_128<1><<<dim3(512 / 128, 4096 / 128), 256, 0, stream>>>(
            all_embeds, semantic_W, em, 4096, 512, 300, 300, 300, semantic_b, nullptr, 1);
        gemm_f32_128<0><<<dim3(1024 / 128, 4096 / 128), 256, 0, stream>>>(
            em, gc1_W + (size_t)512 * 1024, Y1, 4096, 1024, 512, 512, 1024,
            nullptr, ws + OFF_VROW, 0);
        gemm_f32_128<0><<<dim3(1024 / 128, 4096 / 128), 256, 0, stream>>>(
            adj, Y1, H1, 4096, 1024, 4096, 4096, 1024, gc1_b, nullptr, 1);
        gemm_f32_128<0><<<dim3(1024 / 128, 4096 / 128), 256, 0, stream>>>(
            H1, gc2_W, Y2, 4096, 1024, 1024, 1024, 1024, nullptr, nullptr, 0);
        gemm_f32_128<0><<<dim3(1024 / 128, 4096 / 128), 256, 0, stream>>>(
            adj, Y2, H2, 4096, 1024, 4096, 4096, 1024, gc2_b, nullptr, 1);
        y3_kernel<<<4096, 256, 0, stream>>>(H2, gc3_W, ws);
        h3_kernel<<<4096, 256, 0, stream>>>(adj, gc3_b, ws);
        gcn_kernel<<<512, 256, 0, stream>>>(gcn512_W, gcn512_b, ws);
        x_kernel<<<512, 256, 0, stream>>>(hidden_W, hidden_b, ws);
        out_kernel<<<1, 512, 0, stream>>>(ws, critic_W, critic_b, actor_W, actor_b, out);
    }

    (void)in_sizes; (void)n_in; (void)out_size;
}

// Round 4
// 191.808 us; speedup vs baseline: 13.8910x; 1.2334x over previous
//
#include <hip/hip_runtime.h>
#include <cstddef>
#include <cstdint>

typedef short  s16x8 __attribute__((ext_vector_type(8)));
typedef float  f32x4 __attribute__((ext_vector_type(4)));
typedef unsigned short u16x4 __attribute__((ext_vector_type(4)));

typedef __attribute__((address_space(1))) const void gas_void;
typedef __attribute__((address_space(3))) void las_void;

// ---------------- bf16 helpers ----------------
__device__ __forceinline__ unsigned short f2bh(float x) {
    union { float f; unsigned int u; } c; c.f = x;
    unsigned int r = c.u + 0x7fffu + ((c.u >> 16) & 1u);
    return (unsigned short)(r >> 16);
}
__device__ __forceinline__ float bh2f(unsigned short h) {
    union { unsigned int u; float f; } c; c.u = ((unsigned int)h) << 16;
    return c.f;
}
__device__ __forceinline__ f32x4 MF(s16x8 a, s16x8 b, f32x4 c) {
    return __builtin_amdgcn_mfma_f32_16x16x32_bf16(a, b, c, 0, 0, 0);
}
__device__ __forceinline__ void gload16(const unsigned short* g, unsigned short* l) {
    __builtin_amdgcn_global_load_lds((gas_void*)g, (las_void*)l, 16, 0, 0);
}

// ---------------- vec region offsets (floats) ----------------
static constexpr size_t OFF_VIS  = 0;
static constexpr size_t OFF_SEM  = 512;
static constexpr size_t OFF_GCN  = 1024;
static constexpr size_t OFF_S512 = 1536;
static constexpr size_t OFF_VROW = 2048;
static constexpr size_t OFF_X    = 3072;
static constexpr size_t OFF_Y3   = 4096;
static constexpr size_t OFF_H3   = 8192;
// fallback big buffers (floats, absolute in ws)
static constexpr size_t OFF_BUF0 = 16384;
static constexpr size_t OFF_BUF1 = OFF_BUF0 + 4194304;
static constexpr size_t OFF_BUF2 = OFF_BUF1 + 4194304;

// ---------------- fast-path ws layout (bytes) ----------------
static constexpr size_t F_ADJH  = 0;                          // 4096*4096*2 = 33554432
static constexpr size_t F_EMB_H = F_ADJH + 33554432;          // 4096*320*2 = 2621440
static constexpr size_t F_EMB_L = F_EMB_H + 2621440;
static constexpr size_t F_SW_H  = F_EMB_L + 2621440;          // 512*320*2 = 327680
static constexpr size_t F_SW_L  = F_SW_H + 327680;
static constexpr size_t F_W1T_H = F_SW_L + 327680;            // 1024*512*2 = 1048576
static constexpr size_t F_W1T_L = F_W1T_H + 1048576;
static constexpr size_t F_W2T_H = F_W1T_L + 1048576;          // 1024*1024*2 = 2097152
static constexpr size_t F_EMT   = F_W2T_H + 2097152;          // 512*4096*2 = 4194304
static constexpr size_t F_P1_H  = F_EMT + 4194304;            // 4096*512*2
static constexpr size_t F_P1_L  = F_P1_H + 4194304;
static constexpr size_t F_H1    = F_P1_L + 4194304;           // 4096*1024*2 = 8388608
static constexpr size_t F_Y2T   = F_H1 + 8388608;             // 1024*4096*2 = 8388608
static constexpr size_t F_Y3P   = F_Y2T + 8388608;            // 32*4096*4 = 524288
static constexpr size_t F_VEC   = F_Y3P + 524288;             // 12288 floats
static constexpr size_t FAST_WS = F_VEC + 49152;              // ~73.2 MB

// ---------------- block reduction ----------------
__device__ inline float blockReduceSum256(float v) {
    #pragma unroll
    for (int o = 32; o > 0; o >>= 1) v += __shfl_down(v, o, 64);
    __shared__ float red[4];
    int w = threadIdx.x >> 6;
    if ((threadIdx.x & 63) == 0) red[w] = v;
    __syncthreads();
    if (threadIdx.x == 0) v = red[0] + red[1] + red[2] + red[3];
    return v;
}

// ---------------- vec3 body (shared by standalone kernel and prep) ----------------
__device__ __forceinline__ void vec3_body(int b,
                            const float* __restrict__ frames,
                            const float* __restrict__ scores,
                            const float* __restrict__ word_embed,
                            const float* __restrict__ visual_W, const float* __restrict__ visual_b,
                            const float* __restrict__ semantic_W, const float* __restrict__ semantic_b,
                            const float* __restrict__ score_W, const float* __restrict__ score_b,
                            float* __restrict__ vec) {
    const float* x; const float* W; const float* bias; float* out; int K; int row;
    if (b < 512)       { row = b;        x = frames;     W = visual_W;   bias = visual_b;   out = vec + OFF_VIS;  K = 8192; }
    else if (b < 1024) { row = b - 512;  x = word_embed; W = semantic_W; bias = semantic_b; out = vec + OFF_SEM;  K = 300;  }
    else               { row = b - 1024; x = scores;     W = score_W;    bias = score_b;    out = vec + OFF_S512; K = 1000; }
    const float* wr = W + (size_t)row * K;
    float s = 0.f;
    for (int k = threadIdx.x; k < K; k += 256) s += wr[k] * x[k];
    s = blockReduceSum256(s);
    if (threadIdx.x == 0) out[row] = fmaxf(s + bias[row], 0.f);
}

// ---------------- small kernels ----------------
__global__ void vec3_kernel(const float* __restrict__ frames,
                            const float* __restrict__ scores,
                            const float* __restrict__ word_embed,
                            const float* __restrict__ visual_W, const float* __restrict__ visual_b,
                            const float* __restrict__ semantic_W, const float* __restrict__ semantic_b,
                            const float* __restrict__ score_W, const float* __restrict__ score_b,
                            float* __restrict__ vec) {
    vec3_body(blockIdx.x, frames, scores, word_embed, visual_W, visual_b,
              semantic_W, semantic_b, score_W, score_b, vec);
}

__global__ void vrow_kernel(const float* __restrict__ gc1_W, float* __restrict__ vec) {
    int j = blockIdx.x * 256 + threadIdx.x;
    const float* s512 = vec + OFF_S512;
    float s = 0.f;
    for (int k = 0; k < 512; k++) s += s512[k] * gc1_W[(size_t)k * 1024 + j];
    vec[OFF_VROW + j] = s;
}

__global__ void y3_kernel(const float* __restrict__ H2, const float* __restrict__ gc3_W,
                          float* __restrict__ vec) {
    int i = blockIdx.x;
    const float* r = H2 + (size_t)i * 1024;
    float s = 0.f;
    for (int k = threadIdx.x; k < 1024; k += 256) s += r[k] * gc3_W[k];
    s = blockReduceSum256(s);
    if (threadIdx.x == 0) vec[OFF_Y3 + i] = s;
}

// y3 partial reduction (fast path): vec[Y3+i] = sum_p y3p[p][i]
__global__ void y3red_kernel(const float* __restrict__ y3p, float* __restrict__ vec) {
    int i = blockIdx.x * 256 + threadIdx.x;
    float s = 0.f;
    #pragma unroll
    for (int p = 0; p < 32; p++) s += y3p[(size_t)p * 4096 + i];
    vec[OFF_Y3 + i] = s;
}

// h3 from bf16 adj
__global__ void h3b_kernel(const unsigned short* __restrict__ adj_h,
                           const float* __restrict__ gc3_b, float* __restrict__ vec) {
    int i = blockIdx.x;
    const u16x4* rp = (const u16x4*)(adj_h + (size_t)i * 4096);
    const float* y3 = vec + OFF_Y3;
    float s = 0.f;
    for (int c = threadIdx.x; c < 1024; c += 256) {
        u16x4 v = rp[c];
        int k0 = c * 4;
        s += bh2f(v[0]) * y3[k0] + bh2f(v[1]) * y3[k0 + 1]
           + bh2f(v[2]) * y3[k0 + 2] + bh2f(v[3]) * y3[k0 + 3];
    }
    s = blockReduceSum256(s);
    if (threadIdx.x == 0) vec[OFF_H3 + i] = fmaxf(s + gc3_b[0], 0.f);
}

__global__ void h3_kernel(const float* __restrict__ adj, const float* __restrict__ gc3_b,
                          float* __restrict__ vec) {
    int i = blockIdx.x;
    const float* r = adj + (size_t)i * 4096;
    const float* y3 = vec + OFF_Y3;
    float s = 0.f;
    for (int k = threadIdx.x; k < 4096; k += 256) s += r[k] * y3[k];
    s = blockReduceSum256(s);
    if (threadIdx.x == 0) vec[OFF_H3 + i] = fmaxf(s + gc3_b[0], 0.f);
}

__global__ void gcn_kernel(const float* __restrict__ gcn512_W, const float* __restrict__ gcn512_b,
                           float* __restrict__ vec) {
    int j = blockIdx.x;
    const float* r = gcn512_W + (size_t)j * 4096;
    const float* h3 = vec + OFF_H3;
    float s = 0.f;
    for (int k = threadIdx.x; k < 4096; k += 256) s += r[k] * h3[k];
    s = blockReduceSum256(s);
    if (threadIdx.x == 0) vec[OFF_GCN + j] = fmaxf(s + gcn512_b[j], 0.f);
}

__global__ void x_kernel(const float* __restrict__ hidden_W, const float* __restrict__ hidden_b,
                         float* __restrict__ vec) {
    int j = blockIdx.x;
    const float* r = hidden_W + (size_t)j * 1536;
    const float* joint = vec;
    float s = 0.f;
    for (int k = threadIdx.x; k < 1536; k += 256) s += r[k] * joint[k];
    s = blockReduceSum256(s);
    if (threadIdx.x == 0) vec[OFF_X + j] = fmaxf(s + hidden_b[j], 0.f);
}

__global__ void out_kernel(const float* __restrict__ vec,
                           const float* __restrict__ critic_W, const float* __restrict__ critic_b,
                           const float* __restrict__ actor_W, const float* __restrict__ actor_b,
                           float* __restrict__ out) {
    const float* xv = vec + OFF_X;
    int w = threadIdx.x >> 6, l = threadIdx.x & 63;
    if (w >= 7) return;
    const float* row = (w == 0) ? critic_W : actor_W + (size_t)(w - 1) * 512;
    float s = 0.f;
    for (int q = l; q < 512; q += 64) s += xv[q] * row[q];
    #pragma unroll
    for (int o = 32; o > 0; o >>= 1) s += __shfl_down(s, o, 64);
    if (l == 0) out[w] = s + ((w == 0) ? critic_b[0] : actor_b[w - 1]);
}

// ---------------- fused prep kernel: all converts + vec3 ----------------
// grid partitions: [0,16384) adj cvt | [,+5120) emb split | [,+640) sw split |
// [,+512) w1T hi+lo | [,+1024) w2T hi | [,+1536) vec3
__global__ void prep_kernel(const float* __restrict__ adj,
                            const float* __restrict__ all_embeds,
                            const float* __restrict__ semantic_W,
                            const float* __restrict__ gc1_W,
                            const float* __restrict__ gc2_W,
                            const float* __restrict__ frames,
                            const float* __restrict__ scores,
                            const float* __restrict__ word_embed,
                            const float* __restrict__ visual_W, const float* __restrict__ visual_b,
                            const float* __restrict__ semantic_b,
                            const float* __restrict__ score_W, const float* __restrict__ score_b,
                            unsigned short* __restrict__ adj_h,
                            unsigned short* __restrict__ emb_h, unsigned short* __restrict__ emb_l,
                            unsigned short* __restrict__ sw_h, unsigned short* __restrict__ sw_l,
                            unsigned short* __restrict__ w1t_h, unsigned short* __restrict__ w1t_l,
                            unsigned short* __restrict__ w2t_h,
                            float* __restrict__ vec) {
    __shared__ float tile[32][33];
    const int b = blockIdx.x, t = threadIdx.x;
    if (b < 16384) {
        size_t i = (size_t)b * 256 + t;
        float4 v = ((const float4*)adj)[i];
        u16x4 h; h[0] = f2bh(v.x); h[1] = f2bh(v.y); h[2] = f2bh(v.z); h[3] = f2bh(v.w);
        *(u16x4*)(adj_h + i * 4) = h;
    } else if (b < 16384 + 5120) {
        size_t i = (size_t)(b - 16384) * 256 + t;   // over 4096*320
        int r = (int)(i / 320), c = (int)(i % 320);
        float v = (c < 300) ? all_embeds[(size_t)r * 300 + c] : 0.f;
        unsigned short h = f2bh(v);
        emb_h[i] = h; emb_l[i] = f2bh(v - bh2f(h));
    } else if (b < 16384 + 5120 + 640) {
        size_t i = (size_t)(b - 16384 - 5120) * 256 + t;   // over 512*320
        int r = (int)(i / 320), c = (int)(i % 320);
        float v = (c < 300) ? semantic_W[(size_t)r * 300 + c] : 0.f;
        unsigned short h = f2bh(v);
        sw_h[i] = h; sw_l[i] = f2bh(v - bh2f(h));
    } else if (b < 16384 + 5120 + 640 + 512) {
        // w1T: src = gc1_W[512:,:] f32 [K=512, N=1024] -> [N,K] hi+lo
        int l2 = b - 16384 - 5120 - 640;
        const float* src = gc1_W + (size_t)512 * 1024;
        int kb = (l2 & 15) * 32, nb = (l2 >> 4) * 32;
        int tx = t & 31, ty = t >> 5;
        #pragma unroll
        for (int i = 0; i < 32; i += 8)
            tile[ty + i][tx] = src[(size_t)(kb + ty + i) * 1024 + nb + tx];
        __syncthreads();
        #pragma unroll
        for (int i = 0; i < 32; i += 8) {
            int n = nb + ty + i, k = kb + tx;
            float v = tile[tx][ty + i];
            unsigned short h = f2bh(v);
            w1t_h[(size_t)n * 512 + k] = h;
            w1t_l[(size_t)n * 512 + k] = f2bh(v - bh2f(h));
        }
    } else if (b < 16384 + 5120 + 640 + 512 + 1024) {
        // w2T: gc2_W f32 [1024,1024] -> [N,K] hi
        int l2 = b - 16384 - 5120 - 640 - 512;
        int kb = (l2 & 31) * 32, nb = (l2 >> 5) * 32;
        int tx = t & 31, ty = t >> 5;
        #pragma unroll
        for (int i = 0; i < 32; i += 8)
            tile[ty + i][tx] = gc2_W[(size_t)(kb + ty + i) * 1024 + nb + tx];
        __syncthreads();
        #pragma unroll
        for (int i = 0; i < 32; i += 8) {
            int n = nb + ty + i, k = kb + tx;
            w2t_h[(size_t)n * 1024 + k] = f2bh(tile[tx][ty + i]);
        }
    } else {
        vec3_body(b - (16384 + 5120 + 640 + 512 + 1024), frames, scores, word_embed,
                  visual_W, visual_b, semantic_W, semantic_b, score_W, score_b, vec);
    }
}

// ---------------- staging helper ----------------
template<int NCHP, int NJ>
__device__ __forceinline__ void stg_mat(const unsigned short* __restrict__ src, int ld, int r0,
                                        int k0, unsigned short* dst, int t) {
    #pragma unroll
    for (int j = 0; j < NJ; j++) {
        int c = j * 256 + t;
        int p = c / NCHP;
        int idx = c % NCHP;
        int row = idx >> 2;
        int gg = (idx & 3) ^ ((row >> 1) & 3);
        gload16(src + (size_t)(r0 + row) * ld + (k0 + p * 32 + gg * 8),
                dst + (size_t)(j * 256 + (t & ~63)) * 8);
    }
}

template<int ROWS>
__device__ __forceinline__ s16x8 rfrag(const unsigned short* rb, int row, int p, int g4) {
    int byte = (p * ROWS + row) * 64 + ((g4 ^ ((row >> 1) & 3)) << 4);
    return *(const s16x8*)((const char*)rb + byte);
}

// ---------------- MFMA bf16 GEMM, BMx64 tile, BK-deep, ring-3 counted-vmcnt ----------------
// C[M,N] = A[M,K] @ B^T ; A,B bf16, K-contiguous rows (NT).
// PROD: 1 = Ah*Bh ; 3 = Ah*Bh + Ah*Bl + Al*Bh
// WMODE: 1 hi+lo C[m][n]; 3 hi C[m][n]; 4 hi C^T[n][m] (ldc=M); 5 fused y3 partials
template<int BM, int BK, int PROD, int WMODE, int RELU>
__global__ __launch_bounds__(256) void mfma_gemm(
    const unsigned short* __restrict__ Ah, const unsigned short* __restrict__ Al,
    const unsigned short* __restrict__ Bh, const unsigned short* __restrict__ Bl,
    int K, int lda, int ldb,
    unsigned short* __restrict__ Ch, unsigned short* __restrict__ Cl, int ldc,
    const float* __restrict__ bias, const float* __restrict__ bias2,
    const float* __restrict__ w3, float* __restrict__ y3p)
{
    constexpr int A_USH = BM * BK;
    constexpr int B_USH = 64 * BK;
    constexpr int A_CH  = A_USH / 8;
    constexpr int B_CH  = B_USH / 8;
    constexpr int SLOT  = (PROD == 3) ? 2 * (A_USH + B_USH) : (A_USH + B_USH);
    constexpr int L     = ((A_CH + B_CH) / 256) * ((PROD == 3) ? 2 : 1);   // loads/thread/stage
    constexpr int FM    = BM / 32;   // frags along M per wave
    __shared__ unsigned short lds[3 * SLOT];

    const int t = threadIdx.x;
    const int w = t >> 6, l = t & 63;
    const int r = l & 15, g4 = l >> 4;
    const int wr = (w >> 1) * (BM / 2);
    const int wc = (w & 1) * 32;

    // XCD-aware bijective swizzle (nwg multiple of 8 in all our launches)
    const int gx = gridDim.x;
    const int nwg = gx * gridDim.y;
    int flat = blockIdx.y * gx + blockIdx.x;
    int swz = (flat & 7) * (nwg >> 3) + (flat >> 3);
    const int col0 = (swz % gx) * 64;
    const int row0 = (swz / gx) * BM;

    f32x4 acc[FM][2];
    #pragma unroll
    for (int a = 0; a < FM; a++)
        #pragma unroll
        for (int b = 0; b < 2; b++) acc[a][b] = (f32x4){0.f, 0.f, 0.f, 0.f};

    auto stage = [&](int slot, int k0) {
        unsigned short* base = lds + slot * SLOT;
        stg_mat<BM * 4, A_CH / 256>(Ah, lda, row0, k0, base, t);
        stg_mat<256,    B_CH / 256>(Bh, ldb, col0, k0, base + A_USH, t);
        if constexpr (PROD == 3) {
            stg_mat<256,    B_CH / 256>(Bl, ldb, col0, k0, base + A_USH + B_USH, t);
            stg_mat<BM * 4, A_CH / 256>(Al, lda, row0, k0, base + A_USH + 2 * B_USH, t);
        }
    };

    const int T = K / BK;
    stage(0, 0);
    stage(1, BK);

    for (int tt = 0; tt < T; ++tt) {
        __builtin_amdgcn_s_barrier();                 // all waves done with slot (tt+2)%3
        if (tt + 2 < T) {
            stage((tt + 2) % 3, (tt + 2) * BK);
            if constexpr (L == 4) asm volatile("s_waitcnt vmcnt(8)" ::: "memory");
            else                  asm volatile("s_waitcnt vmcnt(12)" ::: "memory");
        } else if (tt + 1 < T) {
            if constexpr (L == 4) asm volatile("s_waitcnt vmcnt(4)" ::: "memory");
            else                  asm volatile("s_waitcnt vmcnt(6)" ::: "memory");
        } else {
            asm volatile("s_waitcnt vmcnt(0)" ::: "memory");
        }
        __builtin_amdgcn_s_barrier();                 // slot tt staged for everyone

        const unsigned short* base = lds + (tt % 3) * SLOT;
        #pragma unroll
        for (int kk = 0; kk < BK / 32; kk++) {
            s16x8 a[FM], bb[2], alr[FM], blr[2];
            #pragma unroll
            for (int f = 0; f < FM; f++) a[f] = rfrag<BM>(base, wr + f * 16 + r, kk, g4);
            #pragma unroll
            for (int f = 0; f < 2; f++) bb[f] = rfrag<64>(base + A_USH, wc + f * 16 + r, kk, g4);
            if constexpr (PROD == 3) {
                #pragma unroll
                for (int f = 0; f < 2; f++) blr[f] = rfrag<64>(base + A_USH + B_USH, wc + f * 16 + r, kk, g4);
                #pragma unroll
                for (int f = 0; f < FM; f++) alr[f] = rfrag<BM>(base + A_USH + 2 * B_USH, wr + f * 16 + r, kk, g4);
            }
            __builtin_amdgcn_s_setprio(1);
            #pragma unroll
            for (int fm = 0; fm < FM; fm++)
                #pragma unroll
                for (int fn = 0; fn < 2; fn++) {
                    acc[fm][fn] = MF(a[fm], bb[fn], acc[fm][fn]);
                    if constexpr (PROD == 3) {
                        acc[fm][fn] = MF(a[fm], blr[fn], acc[fm][fn]);
                        acc[fm][fn] = MF(alr[fm], bb[fn], acc[fm][fn]);
                    }
                }
            __builtin_amdgcn_s_setprio(0);
        }
    }

    // epilogue (C/D: col = lane&15, row = 4*(lane>>4)+i — m89-verified)
    if constexpr (WMODE == 5) {
        float yacc[FM][4];
        #pragma unroll
        for (int fm = 0; fm < FM; fm++)
            #pragma unroll
            for (int i = 0; i < 4; i++) yacc[fm][i] = 0.f;
        #pragma unroll
        for (int fn = 0; fn < 2; fn++) {
            int n = col0 + wc + fn * 16 + r;
            float bn = bias[n];
            float wn = w3[n];
            #pragma unroll
            for (int fm = 0; fm < FM; fm++) {
                f32x4 v = acc[fm][fn];
                #pragma unroll
                for (int i = 0; i < 4; i++) {
                    float x = fmaxf(v[i] + bn, 0.f);
                    yacc[fm][i] += x * wn;
                }
            }
        }
        int slot = (col0 >> 6) * 2 + (w & 1);
        #pragma unroll
        for (int fm = 0; fm < FM; fm++)
            #pragma unroll
            for (int i = 0; i < 4; i++) {
                float v = yacc[fm][i];
                v += __shfl_xor(v, 1, 64);
                v += __shfl_xor(v, 2, 64);
                v += __shfl_xor(v, 4, 64);
                v += __shfl_xor(v, 8, 64);
                if ((l & 15) == 0)
                    y3p[(size_t)slot * 4096 + row0 + wr + fm * 16 + g4 * 4 + i] = v;
            }
    } else {
        #pragma unroll
        for (int fn = 0; fn < 2; fn++) {
            int n = col0 + wc + fn * 16 + r;
            float bn = bias ? bias[n] : 0.f;
            if (bias2) bn += bias2[n];
            #pragma unroll
            for (int fm = 0; fm < FM; fm++) {
                int m0 = row0 + wr + fm * 16 + g4 * 4;
                f32x4 v = acc[fm][fn];
                if constexpr (WMODE == 4) {
                    u16x4 hv;
                    #pragma unroll
                    for (int i = 0; i < 4; i++) {
                        float x = v[i] + bn;
                        if (RELU) x = fmaxf(x, 0.f);
                        hv[i] = f2bh(x);
                    }
                    *(u16x4*)(Ch + (size_t)n * ldc + m0) = hv;
                } else {
                    #pragma unroll
                    for (int i = 0; i < 4; i++) {
                        float x = v[i] + bn;
                        if (RELU) x = fmaxf(x, 0.f);
                        int m = m0 + i;
                        if constexpr (WMODE == 1) {
                            unsigned short h = f2bh(x);
                            Ch[(size_t)m * ldc + n] = h;
                            Cl[(size_t)m * ldc + n] = f2bh(x - bh2f(h));
                        } else {  // WMODE 3
                            Ch[(size_t)m * ldc + n] = f2bh(x);
                        }
                    }
                }
            }
        }
    }
}

// ---------------- fallback f32 tiled GEMM (round-1, proven) ----------------
template<int TRANSB>
__global__ __launch_bounds__(256) void gemm_f32_128(
    const float* __restrict__ A, const float* __restrict__ B, float* __restrict__ C,
    int M, int N, int K, int lda, int ldb,
    const float* __restrict__ bias, const float* __restrict__ vrow, int do_relu)
{
    constexpr int BM = 128, BN = 128, BK = 16;
    __shared__ float As[BK][BM + 4];
    __shared__ float Bs[BK][BN + 4];
    const int t = threadIdx.x;
    const int w = t >> 6, l = t & 63;
    const int cx = (w & 1) * 8 + (l & 7);
    const int cy = (w >> 1) * 8 + (l >> 3);
    const int row0 = blockIdx.y * BM;
    const int col0 = blockIdx.x * BN;

    float acc[8][8];
    #pragma unroll
    for (int i = 0; i < 8; i++)
        #pragma unroll
        for (int j = 0; j < 8; j++) acc[i][j] = 0.f;

    const int ka = t & 15;
    const int ma = t >> 4;

    for (int k0 = 0; k0 < K; k0 += BK) {
        #pragma unroll
        for (int i = 0; i < 8; i++) {
            int m = ma + i * 16;
            int gk = k0 + ka;
            float v = 0.f;
            if (gk < K) v = A[(size_t)(row0 + m) * lda + gk];
            As[ka][m] = v;
        }
        if (TRANSB) {
            #pragma unroll
            for (int i = 0; i < 8; i++) {
                int n = ma + i * 16;
                int gk = k0 + ka;
                float v = 0.f;
                if (gk < K) v = B[(size_t)(col0 + n) * ldb + gk];
                Bs[ka][n] = v;
            }
        } else {
            const int nb = t & 127;
            const int kb = t >> 7;
            #pragma unroll
            for (int i = 0; i < 8; i++) {
                int kk = kb + i * 2;
                int gk = k0 + kk;
                float v = 0.f;
                if (gk < K) v = B[(size_t)gk * ldb + col0 + nb];
                Bs[kk][nb] = v;
            }
        }
        __syncthreads();
        #pragma unroll
        for (int kk = 0; kk < BK; kk++) {
            float a[8], bb[8];
            *(float4*)&a[0]  = *(const float4*)&As[kk][cy * 8];
            *(float4*)&a[4]  = *(const float4*)&As[kk][cy * 8 + 4];
            *(float4*)&bb[0] = *(const float4*)&Bs[kk][cx * 8];
            *(float4*)&bb[4] = *(const float4*)&Bs[kk][cx * 8 + 4];
            #pragma unroll
            for (int i = 0; i < 8; i++)
                #pragma unroll
                for (int j = 0; j < 8; j++)
                    acc[i][j] = fmaf(a[i], bb[j], acc[i][j]);
        }
        __syncthreads();
    }

    #pragma unroll
    for (int i = 0; i < 8; i++) {
        int rr = row0 + cy * 8 + i;
        float vv[8];
        #pragma unroll
        for (int j = 0; j < 8; j++) {
            int c = col0 + cx * 8 + j;
            float v = acc[i][j];
            if (vrow) v += vrow[c];
            if (bias) v += bias[c];
            if (do_relu) v = fmaxf(v, 0.f);
            vv[j] = v;
        }
        float* cp = C + (size_t)rr * N + col0 + cx * 8;
        *(float4*)cp       = *(float4*)&vv[0];
        *(float4*)(cp + 4) = *(float4*)&vv[4];
    }
}

// ---------------- host launcher ----------------
extern "C" void kernel_launch(void* const* d_in, const int* in_sizes, int n_in,
                              void* d_out, int out_size, void* d_ws, size_t ws_size,
                              hipStream_t stream) {
    const float* frames     = (const float*)d_in[0];
    const float* scores     = (const float*)d_in[1];
    const float* word_embed = (const float*)d_in[2];
    const float* all_embeds = (const float*)d_in[3];
    const float* adj        = (const float*)d_in[4];
    const float* visual_W   = (const float*)d_in[5];
    const float* visual_b   = (const float*)d_in[6];
    const float* semantic_W = (const float*)d_in[7];
    const float* semantic_b = (const float*)d_in[8];
    const float* score_W    = (const float*)d_in[9];
    const float* score_b    = (const float*)d_in[10];
    const float* gc1_W      = (const float*)d_in[11];
    const float* gc1_b      = (const float*)d_in[12];
    const float* gc2_W      = (const float*)d_in[13];
    const float* gc2_b      = (const float*)d_in[14];
    const float* gc3_W      = (const float*)d_in[15];
    const float* gc3_b      = (const float*)d_in[16];
    const float* gcn512_W   = (const float*)d_in[17];
    const float* gcn512_b   = (const float*)d_in[18];
    const float* hidden_W   = (const float*)d_in[19];
    const float* hidden_b   = (const float*)d_in[20];
    const float* critic_W   = (const float*)d_in[21];
    const float* critic_b   = (const float*)d_in[22];
    const float* actor_W    = (const float*)d_in[23];
    const float* actor_b    = (const float*)d_in[24];

    float* out = (float*)d_out;

    if (ws_size >= FAST_WS) {
        char* wsb = (char*)d_ws;
        unsigned short* adj_h = (unsigned short*)(wsb + F_ADJH);
        unsigned short* emb_h = (unsigned short*)(wsb + F_EMB_H);
        unsigned short* emb_l = (unsigned short*)(wsb + F_EMB_L);
        unsigned short* sw_h  = (unsigned short*)(wsb + F_SW_H);
        unsigned short* sw_l  = (unsigned short*)(wsb + F_SW_L);
        unsigned short* w1t_h = (unsigned short*)(wsb + F_W1T_H);
        unsigned short* w1t_l = (unsigned short*)(wsb + F_W1T_L);
        unsigned short* w2t_h = (unsigned short*)(wsb + F_W2T_H);
        unsigned short* emT   = (unsigned short*)(wsb + F_EMT);
        unsigned short* p1_h  = (unsigned short*)(wsb + F_P1_H);
        unsigned short* p1_l  = (unsigned short*)(wsb + F_P1_L);
        unsigned short* h1    = (unsigned short*)(wsb + F_H1);
        unsigned short* y2t   = (unsigned short*)(wsb + F_Y2T);
        float*          y3p   = (float*)(wsb + F_Y3P);
        float*          vec   = (float*)(wsb + F_VEC);

        // 1. prep: all converts + vec3
        prep_kernel<<<16384 + 5120 + 640 + 512 + 1024 + 1536, 256, 0, stream>>>(
            adj, all_embeds, semantic_W, gc1_W, gc2_W,
            frames, scores, word_embed, visual_W, visual_b, semantic_b, score_W, score_b,
            adj_h, emb_h, emb_l, sw_h, sw_l, w1t_h, w1t_l, w2t_h, vec);
        // 2. vrow = s512 @ gc1_W[:512,:]
        vrow_kernel<<<4, 256, 0, stream>>>(gc1_W, vec);
        // 3. emT = relu(all_embeds @ semantic_W^T + b)^T  hi [512,4096], K=320
        mfma_gemm<64, 32, 3, 4, 1><<<dim3(8, 64), 256, 0, stream>>>(
            emb_h, emb_l, sw_h, sw_l, 320, 320, 320,
            emT, nullptr, 4096, semantic_b, nullptr, nullptr, nullptr);
        // 4. P1 = adj @ em  hi+lo [4096,512], K=4096
        mfma_gemm<64, 64, 1, 1, 0><<<dim3(8, 64), 256, 0, stream>>>(
            adj_h, nullptr, emT, nullptr, 4096, 4096, 4096,
            p1_h, p1_l, 512, nullptr, nullptr, nullptr, nullptr);
        // 5. h1 = relu(P1 @ W1' + vrow + b1)  hi [4096,1024], K=512
        mfma_gemm<128, 32, 3, 3, 1><<<dim3(16, 32), 256, 0, stream>>>(
            p1_h, p1_l, w1t_h, w1t_l, 512, 512, 512,
            h1, nullptr, 1024, gc1_b, vec + OFF_VROW, nullptr, nullptr);
        // 6. y2t = (h1 @ gc2_W)^T  hi [1024,4096], K=1024
        mfma_gemm<128, 64, 1, 4, 0><<<dim3(16, 32), 256, 0, stream>>>(
            h1, nullptr, w2t_h, nullptr, 1024, 1024, 1024,
            y2t, nullptr, 4096, nullptr, nullptr, nullptr, nullptr);
        // 7. fused: H2 = relu(adj @ Y2 + b2); y3 partials = H2 @ gc3_W  (K=4096)
        mfma_gemm<128, 64, 1, 5, 1><<<dim3(16, 32), 256, 0, stream>>>(
            adj_h, nullptr, y2t, nullptr, 4096, 4096, 4096,
            nullptr, nullptr, 0, gc2_b, nullptr, gc3_W, y3p);
        // 8. y3 = sum of partials
        y3red_kernel<<<16, 256, 0, stream>>>(y3p, vec);
        // 9-12. tail
        h3b_kernel<<<4096, 256, 0, stream>>>(adj_h, gc3_b, vec);
        gcn_kernel<<<512, 256, 0, stream>>>(gcn512_W, gcn512_b, vec);
        x_kernel<<<512, 256, 0, stream>>>(hidden_W, hidden_b, vec);
        out_kernel<<<1, 512, 0, stream>>>(vec, critic_W, critic_b, actor_W, actor_b, out);
    } else {
        // fallback f32 path (round-1, proven within 50.4 MB)
        float* ws = (float*)d_ws;
        float* em = ws + OFF_BUF0;
        float* Y1 = ws + OFF_BUF1;
        float* H1 = ws + OFF_BUF2;
        float* Y2 = ws + OFF_BUF1;
        float* H2 = ws + OFF_BUF0;

        vec3_kernel<<<1536, 256, 0, stream>>>(frames, scores, word_embed,
                                              visual_W, visual_b, semantic_W, semantic_b,
                                              score_W, score_b, ws);
        vrow_kernel<<<4, 256, 0, stream>>>(gc1_W, ws);
        gemm_f32_128<1><<<dim3(512 / 128, 4096 / 128), 256, 0, stream>>>(
            all_embeds, semantic_W, em, 4096, 512, 300, 300, 300, semantic_b, nullptr, 1);
        gemm_f32_128<0><<<dim3(1024 / 128, 4096 / 128), 256, 0, stream>>>(
            em, gc1_W + (size_t)512 * 1024, Y1, 4096, 1024, 512, 512, 1024,
            nullptr, ws + OFF_VROW, 0);
        gemm_f32_128<0><<<dim3(1024 / 128, 4096 / 128), 256, 0, stream>>>(
            adj, Y1, H1, 4096, 1024, 4096, 4096, 1024, gc1_b, nullptr, 1);
        gemm_f32_128<0><<<dim3(1024 / 128, 4096 / 128), 256, 0, stream>>>(
            H1, gc2_W, Y2, 4096, 1024, 1024, 1024, 1024, nullptr, nullptr, 0);
        gemm_f32_128<0><<<dim3(1024 / 128, 4096 / 128), 256, 0, stream>>>(
            adj, Y2, H2, 4096, 1024, 4096, 4096, 1024, gc2_b, nullptr, 1);
        y3_kernel<<<4096, 256, 0, stream>>>(H2, gc3_W, ws);
        h3_kernel<<<4096, 256, 0, stream>>>(adj, gc3_b, ws);
        gcn_kernel<<<512, 256, 0, stream>>>(gcn512_W, gcn512_b, ws);
        x_kernel<<<512, 256, 0, stream>>>(hidden_W, hidden_b, ws);
        out_kernel<<<1, 512, 0, stream>>>(ws, critic_W, critic_b, actor_W, actor_b, out);
    }

    (void)in_sizes; (void)n_in; (void)out_size;
}